// Round 1
// baseline (1877.795 us; speedup 1.0000x reference)
//
#include <hip/hip_runtime.h>
#include <math.h>

namespace {

constexpr int NN = 100000;   // nodes
constexpr int NE = 1200000;  // edges
constexpr int NH = 10000;    // hyperedges
constexpr int NI = 1200000;  // incidences
constexpr int D  = 64;       // hidden dim
constexpr int C  = 40;       // classes

// ---- degree helpers -------------------------------------------------------

__global__ void k_count(const int* __restrict__ idx, float* __restrict__ cnt, int n) {
    int t = blockIdx.x * blockDim.x + threadIdx.x;
    if (t < n) atomicAdd(&cnt[idx[t]], 1.0f);
}

// d holds incoming-edge count; GCN degree = count + 1 (self loop)
__global__ void k_gcn_dinv(float* __restrict__ d, int n) {
    int t = blockIdx.x * blockDim.x + threadIdx.x;
    if (t < n) { float deg = d[t] + 1.0f; d[t] = 1.0f / sqrtf(deg); }
}

__global__ void k_safe_inv(float* __restrict__ d, int n) {
    int t = blockIdx.x * blockDim.x + threadIdx.x;
    if (t < n) { float v = d[t]; d[t] = v > 0.0f ? 1.0f / v : 0.0f; }
}

// ---- GEMM: Y[r][c] = sum_k X[r][k] * W[k][c]  (optionally * scale[r]) -----
// One row per thread; W staged in LDS, read as uniform-broadcast float4.

template <int K, bool SCALE>
__global__ __launch_bounds__(256) void k_gemm(const float* __restrict__ X,
                                              const float* __restrict__ W,
                                              const float* __restrict__ scale,
                                              float* __restrict__ Y, int n) {
    __shared__ float4 Wl[D * K / 4];
    for (int i = threadIdx.x; i < D * K / 4; i += 256)
        Wl[i] = reinterpret_cast<const float4*>(W)[i];
    __syncthreads();

    int r = blockIdx.x * 256 + threadIdx.x;
    if (r >= n) return;

    float xr[D];
    const float4* x4 = reinterpret_cast<const float4*>(X + (size_t)r * D);
#pragma unroll
    for (int i = 0; i < D / 4; ++i) {
        float4 v = x4[i];
        xr[4 * i + 0] = v.x; xr[4 * i + 1] = v.y;
        xr[4 * i + 2] = v.z; xr[4 * i + 3] = v.w;
    }

    float acc[K];
#pragma unroll
    for (int c = 0; c < K; ++c) acc[c] = 0.0f;

#pragma unroll
    for (int k = 0; k < D; ++k) {
        float xv = xr[k];
#pragma unroll
        for (int c4 = 0; c4 < K / 4; ++c4) {
            float4 w = Wl[k * (K / 4) + c4];
            acc[4 * c4 + 0] = fmaf(xv, w.x, acc[4 * c4 + 0]);
            acc[4 * c4 + 1] = fmaf(xv, w.y, acc[4 * c4 + 1]);
            acc[4 * c4 + 2] = fmaf(xv, w.z, acc[4 * c4 + 2]);
            acc[4 * c4 + 3] = fmaf(xv, w.w, acc[4 * c4 + 3]);
        }
    }

    float s = SCALE ? scale[r] : 1.0f;
    float4* y4 = reinterpret_cast<float4*>(Y + (size_t)r * K);
#pragma unroll
    for (int c4 = 0; c4 < K / 4; ++c4) {
        float4 o;
        o.x = acc[4 * c4 + 0] * s; o.y = acc[4 * c4 + 1] * s;
        o.z = acc[4 * c4 + 2] * s; o.w = acc[4 * c4 + 3] * s;
        y4[c4] = o;
    }
}

// ---- scatter-add: A[dst[e]][f] += G[src[e]][f] ----------------------------
// one lane per (edge, feature); 64 lanes per edge, lanes >= K idle.

template <int K>
__global__ void k_scatter(const int* __restrict__ srcI, const int* __restrict__ dstI,
                          const float* __restrict__ G, float* __restrict__ A, int nE) {
    int t = blockIdx.x * blockDim.x + threadIdx.x;
    int e = t >> 6, f = t & 63;
    if (e >= nE) return;
    if (K < 64 && f >= K) return;
    atomicAdd(&A[dstI[e] * K + f], G[srcI[e] * K + f]);
}

// A[node[e]][f] += M[hid[e]][f] * Binv[hid[e]]
template <int K>
__global__ void k_scatter_scaled(const int* __restrict__ hidI, const int* __restrict__ nodeI,
                                 const float* __restrict__ M, const float* __restrict__ Binv,
                                 float* __restrict__ A, int nI) {
    int t = blockIdx.x * blockDim.x + threadIdx.x;
    int e = t >> 6, f = t & 63;
    if (e >= nI) return;
    if (K < 64 && f >= K) return;
    int h = hidI[e];
    atomicAdd(&A[nodeI[e] * K + f], M[h * K + f] * Binv[h]);
}

// ---- finalize: GCN  out = dinv[i]*(acc + g) + b  (out may alias acc) ------

template <int K, bool RELU>
__global__ void k_fin_gcn(const float* acc, const float* g,
                          const float* __restrict__ dinv, const float* __restrict__ b,
                          float* out, int n) {
    int t = blockIdx.x * blockDim.x + threadIdx.x;
    if (t >= n * K) return;
    int i = t / K, c = t - i * K;
    float v = dinv[i] * (acc[t] + g[t]) + b[c];
    if (RELU) v = fmaxf(v, 0.0f);
    out[t] = v;
}

// ---- finalize: hyper  out = acc*Dinv[i] + b  (out may alias acc) ----------

template <int K, bool RELU>
__global__ void k_fin_hyp(const float* acc, const float* __restrict__ Dinv,
                          const float* __restrict__ b, float* out, int n) {
    int t = blockIdx.x * blockDim.x + threadIdx.x;
    if (t >= n * K) return;
    int i = t / K, c = t - i * K;
    float v = acc[t] * Dinv[i] + b[c];
    if (RELU) v = fmaxf(v, 0.0f);
    out[t] = v;
}

// ---- branch attention (K = 64), one node per wave -------------------------

__global__ void k_attn(const float* __restrict__ X, const float* __restrict__ Xh,
                       const float* __restrict__ w, float* __restrict__ out, int n) {
    int t = blockIdx.x * blockDim.x + threadIdx.x;
    int node = t >> 6, lane = t & 63;
    if (node >= n) return;
    float xv = X[t], hv = Xh[t];
    float p0 = xv * w[2 * lane + 0];
    float p1 = hv * w[2 * lane + 1];
#pragma unroll
    for (int o = 32; o; o >>= 1) {
        p0 += __shfl_xor(p0, o, 64);
        p1 += __shfl_xor(p1, o, 64);
    }
    float m = fmaxf(p0, p1);
    float e0 = expf(p0 - m), e1 = expf(p1 - m);
    float inv = 1.0f / (e0 + e1);
    out[t] = (e0 * xv + e1 * hv) * inv;
}

// ---- branch attention (K = 40) + log_softmax, one node per wave -----------

__global__ void k_attn_lsm(const float* __restrict__ X, const float* __restrict__ Xh,
                           const float* __restrict__ w, float* __restrict__ out, int n) {
    int t = blockIdx.x * blockDim.x + threadIdx.x;
    int node = t >> 6, lane = t & 63;
    if (node >= n) return;
    bool act = lane < C;
    int idx = node * C + lane;
    float xv = act ? X[idx] : 0.0f;
    float hv = act ? Xh[idx] : 0.0f;
    float p0 = act ? xv * w[2 * lane + 0] : 0.0f;
    float p1 = act ? hv * w[2 * lane + 1] : 0.0f;
#pragma unroll
    for (int o = 32; o; o >>= 1) {
        p0 += __shfl_xor(p0, o, 64);
        p1 += __shfl_xor(p1, o, 64);
    }
    float m = fmaxf(p0, p1);
    float e0 = expf(p0 - m), e1 = expf(p1 - m);
    float inv = 1.0f / (e0 + e1);
    float v = (e0 * xv + e1 * hv) * inv;

    float mv = act ? v : -1e30f;
#pragma unroll
    for (int o = 32; o; o >>= 1) mv = fmaxf(mv, __shfl_xor(mv, o, 64));
    float ex = act ? expf(v - mv) : 0.0f;
    float s = ex;
#pragma unroll
    for (int o = 32; o; o >>= 1) s += __shfl_xor(s, o, 64);
    float lse = mv + logf(s);
    if (act) out[idx] = v - lse;
}

}  // namespace

extern "C" void kernel_launch(void* const* d_in, const int* in_sizes, int n_in,
                              void* d_out, int out_size, void* d_ws, size_t ws_size,
                              hipStream_t stream) {
    const float* x    = (const float*)d_in[0];
    const int*   ei   = (const int*)d_in[1];
    const int*   esrc = ei;
    const int*   edst = ei + NE;
    const int*   hnode = (const int*)d_in[2];
    const int*   hid   = (const int*)d_in[3];
    const float* W1g = (const float*)d_in[4];
    const float* b1g = (const float*)d_in[5];
    const float* W1h = (const float*)d_in[6];
    const float* b1h = (const float*)d_in[7];
    const float* aw1 = (const float*)d_in[8];
    const float* W2g = (const float*)d_in[9];
    const float* b2g = (const float*)d_in[10];
    const float* W2h = (const float*)d_in[11];
    const float* b2h = (const float*)d_in[12];
    const float* aw2 = (const float*)d_in[13];
    float* out = (float*)d_out;

    char* ws = (char*)d_ws;
    size_t off = 0;
    auto alloc = [&](size_t bytes) -> float* {
        float* p = (float*)(ws + off);
        off = (off + bytes + 255) & ~(size_t)255;
        return p;
    };
    float* dinv = alloc((size_t)NN * 4);
    float* Binv = alloc((size_t)NH * 4);
    float* Dinv = alloc((size_t)NN * 4);
    float* A    = alloc((size_t)NN * D * 4);   // 25.6 MB
    float* Bb   = alloc((size_t)NN * D * 4);
    float* Cc   = alloc((size_t)NN * D * 4);
    float* M    = alloc((size_t)NH * D * 4);   // 2.56 MB

    const int B256 = 256;
    int gNN  = (NN + 255) / 256;
    int gNE  = (NE + 255) / 256;
    int gNI  = (NI + 255) / 256;
    int gE64 = (int)(((size_t)NE * 64) / 256);   // 300000
    int gI64 = (int)(((size_t)NI * 64) / 256);
    int gN64 = NN * 64 / 256;                    // 25000
    int gN40 = (NN * 40 + 255) / 256;

    // ---- degrees (recomputed every call: deterministic) ----
    hipMemsetAsync(dinv, 0, (size_t)NN * 4, stream);
    hipMemsetAsync(Binv, 0, (size_t)NH * 4, stream);
    hipMemsetAsync(Dinv, 0, (size_t)NN * 4, stream);
    k_count<<<gNE, B256, 0, stream>>>(edst, dinv, NE);
    k_count<<<gNI, B256, 0, stream>>>(hid, Binv, NI);
    k_count<<<gNI, B256, 0, stream>>>(hnode, Dinv, NI);
    k_gcn_dinv<<<gNN, B256, 0, stream>>>(dinv, NN);
    k_safe_inv<<<(NH + 255) / 256, B256, 0, stream>>>(Binv, NH);
    k_safe_inv<<<gNN, B256, 0, stream>>>(Dinv, NN);

    // ---- layer 1 GCN: x1 = relu(dinv*(scatter g + g) + b1g), g=(x@W1g)*dinv
    k_gemm<64, true><<<gNN, B256, 0, stream>>>(x, W1g, dinv, A, NN);
    hipMemsetAsync(Bb, 0, (size_t)NN * D * 4, stream);
    k_scatter<64><<<gE64, B256, 0, stream>>>(esrc, edst, A, Bb, NE);
    k_fin_gcn<64, true><<<gN64, B256, 0, stream>>>(Bb, A, dinv, b1g, Bb, NN);
    // Bb = x1

    // ---- layer 1 hypergraph on x1 ----
    k_gemm<64, false><<<gNN, B256, 0, stream>>>(Bb, W1h, nullptr, A, NN);
    hipMemsetAsync(M, 0, (size_t)NH * D * 4, stream);
    k_scatter<64><<<gI64, B256, 0, stream>>>(hnode, hid, A, M, NI);
    hipMemsetAsync(Cc, 0, (size_t)NN * D * 4, stream);
    k_scatter_scaled<64><<<gI64, B256, 0, stream>>>(hid, hnode, M, Binv, Cc, NI);
    k_fin_hyp<64, true><<<gN64, B256, 0, stream>>>(Cc, Dinv, b1h, Cc, NN);
    // Cc = x_hyper

    // ---- attention 1: A = xa ----
    k_attn<<<gN64, B256, 0, stream>>>(Bb, Cc, aw1, A, NN);

    // ---- layer 2 GCN on xa (K=40, no relu) ----
    k_gemm<40, true><<<gNN, B256, 0, stream>>>(A, W2g, dinv, Bb, NN);
    hipMemsetAsync(A, 0, (size_t)NN * 40 * 4, stream);
    k_scatter<40><<<gE64, B256, 0, stream>>>(esrc, edst, Bb, A, NE);
    k_fin_gcn<40, false><<<gN40, B256, 0, stream>>>(A, Bb, dinv, b2g, A, NN);
    // A = x2

    // ---- layer 2 hypergraph on x_hyper (K=40, no relu) ----
    k_gemm<40, false><<<gNN, B256, 0, stream>>>(Cc, W2h, nullptr, Bb, NN);
    hipMemsetAsync(M, 0, (size_t)NH * 40 * 4, stream);
    k_scatter<40><<<gI64, B256, 0, stream>>>(hnode, hid, Bb, M, NI);
    hipMemsetAsync(Cc, 0, (size_t)NN * 40 * 4, stream);
    k_scatter_scaled<40><<<gI64, B256, 0, stream>>>(hid, hnode, M, Binv, Cc, NI);
    k_fin_hyp<40, false><<<gN40, B256, 0, stream>>>(Cc, Dinv, b2h, Cc, NN);
    // Cc = xh2

    // ---- attention 2 + log_softmax -> out ----
    k_attn_lsm<<<gN64, B256, 0, stream>>>(A, Cc, aw2, out, NN);
}

// Round 2
// 1216.468 us; speedup vs baseline: 1.5436x; 1.5436x over previous
//
#include <hip/hip_runtime.h>
#include <math.h>

namespace {

constexpr int NN = 100000;   // nodes
constexpr int NE = 1200000;  // edges
constexpr int NH = 10000;    // hyperedges
constexpr int NI = 1200000;  // incidences
constexpr int D  = 64;       // hidden dim
constexpr int C  = 40;       // classes

// ---- counting (int) -------------------------------------------------------

__global__ void k_count_all(const int* __restrict__ edst, const int* __restrict__ hid,
                            const int* __restrict__ hnode,
                            int* __restrict__ cntE, int* __restrict__ cntH,
                            int* __restrict__ cntN) {
    int t = blockIdx.x * blockDim.x + threadIdx.x;
    if (t < NE) atomicAdd(&cntE[edst[t]], 1);
    if (t < NI) {
        atomicAdd(&cntH[hid[t]], 1);
        atomicAdd(&cntN[hnode[t]], 1);
    }
}

__global__ void k_degs(const int* __restrict__ cntE, const int* __restrict__ cntH,
                       const int* __restrict__ cntN,
                       float* __restrict__ dinv, float* __restrict__ Binv,
                       float* __restrict__ Dinv) {
    int t = blockIdx.x * blockDim.x + threadIdx.x;
    if (t < NN) {
        dinv[t] = rsqrtf((float)cntE[t] + 1.0f);   // +1 self loop
        int c = cntN[t];
        Dinv[t] = c > 0 ? 1.0f / (float)c : 0.0f;
    }
    if (t < NH) {
        int c = cntH[t];
        Binv[t] = c > 0 ? 1.0f / (float)c : 0.0f;
    }
}

// ---- exclusive prefix scan: cnt[0..n) -> rowptr[0..n] ---------------------
// CHUNK = 1024 elements per block (256 threads x 4).

__global__ void k_scan_pass1(const int* __restrict__ cnt, int n, int* __restrict__ bsum) {
    __shared__ int lds[4];
    int base = blockIdx.x * 1024;
    int s = 0;
    for (int i = threadIdx.x; i < 1024; i += 256) {
        int idx = base + i;
        s += (idx < n) ? cnt[idx] : 0;
    }
#pragma unroll
    for (int o = 32; o; o >>= 1) s += __shfl_xor(s, o, 64);
    if ((threadIdx.x & 63) == 0) lds[threadIdx.x >> 6] = s;
    __syncthreads();
    if (threadIdx.x == 0) bsum[blockIdx.x] = lds[0] + lds[1] + lds[2] + lds[3];
}

__global__ void k_scan_bsum(int* __restrict__ bsum, int nb) {
    int lane = threadIdx.x;  // single wave of 64
    int acc = 0;
    for (int base = 0; base < nb; base += 64) {
        int idx = base + lane;
        int v = (idx < nb) ? bsum[idx] : 0;
        int sc = v;
#pragma unroll
        for (int o = 1; o < 64; o <<= 1) {
            int t = __shfl_up(sc, o, 64);
            if (lane >= o) sc += t;
        }
        if (idx < nb) bsum[idx] = acc + sc - v;  // exclusive
        acc += __shfl(sc, 63, 64);
    }
}

// writes rowptr[i] for i in [0, n]; element n is virtual 0 so rowptr[n]=total
__global__ void k_scan_pass3(const int* __restrict__ cnt, int n,
                             const int* __restrict__ bsum, int* __restrict__ rowptr) {
    __shared__ int warpsum[4];
    int lane = threadIdx.x & 63, wid = threadIdx.x >> 6;
    int base = blockIdx.x * 1024 + threadIdx.x * 4;
    int v[4];
    int s = 0;
#pragma unroll
    for (int j = 0; j < 4; ++j) {
        int idx = base + j;
        v[j] = (idx < n) ? cnt[idx] : 0;
        s += v[j];
    }
    int sc = s;
#pragma unroll
    for (int o = 1; o < 64; o <<= 1) {
        int t = __shfl_up(sc, o, 64);
        if (lane >= o) sc += t;
    }
    if (lane == 63) warpsum[wid] = sc;
    __syncthreads();
    int woff = 0;
    for (int w = 0; w < wid; ++w) woff += warpsum[w];
    int excl = bsum[blockIdx.x] + woff + (sc - s);
#pragma unroll
    for (int j = 0; j < 4; ++j) {
        int idx = base + j;
        if (idx <= n) rowptr[idx] = excl;
        excl += v[j];
    }
}

// ---- CSR fill (counting sort) --------------------------------------------

__global__ void k_fill_all(const int* __restrict__ esrc, const int* __restrict__ edst,
                           const int* __restrict__ hid, const int* __restrict__ hnode,
                           const int* __restrict__ rpE, const int* __restrict__ rpH,
                           const int* __restrict__ rpN,
                           int* __restrict__ curE, int* __restrict__ curH,
                           int* __restrict__ curN,
                           int* __restrict__ colE, int* __restrict__ colH,
                           int* __restrict__ colN) {
    int t = blockIdx.x * blockDim.x + threadIdx.x;
    if (t < NE) {
        int d = edst[t];
        int p = rpE[d] + atomicAdd(&curE[d], 1);
        colE[p] = esrc[t];
    }
    if (t < NI) {
        int h = hid[t];
        int p = rpH[h] + atomicAdd(&curH[h], 1);
        colH[p] = hnode[t];
        int nd = hnode[t];
        int q = rpN[nd] + atomicAdd(&curN[nd], 1);
        colN[q] = hid[t];
    }
}

// ---- GEMM: Y[r][c] = (sum_k X[r][k] * W[k][c]) * scale?[r] ----------------

template <int K, bool SCALE>
__global__ __launch_bounds__(256) void k_gemm(const float* __restrict__ X,
                                              const float* __restrict__ W,
                                              const float* __restrict__ scale,
                                              float* __restrict__ Y, int n) {
    __shared__ float4 Wl[D * K / 4];
    for (int i = threadIdx.x; i < D * K / 4; i += 256)
        Wl[i] = reinterpret_cast<const float4*>(W)[i];
    __syncthreads();

    int r = blockIdx.x * 256 + threadIdx.x;
    if (r >= n) return;

    float xr[D];
    const float4* x4 = reinterpret_cast<const float4*>(X + (size_t)r * D);
#pragma unroll
    for (int i = 0; i < D / 4; ++i) {
        float4 v = x4[i];
        xr[4 * i + 0] = v.x; xr[4 * i + 1] = v.y;
        xr[4 * i + 2] = v.z; xr[4 * i + 3] = v.w;
    }

    float acc[K];
#pragma unroll
    for (int c = 0; c < K; ++c) acc[c] = 0.0f;

#pragma unroll
    for (int k = 0; k < D; ++k) {
        float xv = xr[k];
#pragma unroll
        for (int c4 = 0; c4 < K / 4; ++c4) {
            float4 w = Wl[k * (K / 4) + c4];
            acc[4 * c4 + 0] = fmaf(xv, w.x, acc[4 * c4 + 0]);
            acc[4 * c4 + 1] = fmaf(xv, w.y, acc[4 * c4 + 1]);
            acc[4 * c4 + 2] = fmaf(xv, w.z, acc[4 * c4 + 2]);
            acc[4 * c4 + 3] = fmaf(xv, w.w, acc[4 * c4 + 3]);
        }
    }

    float s = SCALE ? scale[r] : 1.0f;
    float4* y4 = reinterpret_cast<float4*>(Y + (size_t)r * K);
#pragma unroll
    for (int c4 = 0; c4 < K / 4; ++c4) {
        float4 o;
        o.x = acc[4 * c4 + 0] * s; o.y = acc[4 * c4 + 1] * s;
        o.z = acc[4 * c4 + 2] * s; o.w = acc[4 * c4 + 3] * s;
        y4[c4] = o;
    }
}

// ---- GCN gather+finalize: out[i] = relu?(dinv[i]*(G[i] + sum_e G[col[e]]) + b)

template <int K, bool RELU>
__global__ void k_gcn_gather(const int* __restrict__ rp, const int* __restrict__ col,
                             const float* __restrict__ G, const float* __restrict__ dinv,
                             const float* __restrict__ b, float* __restrict__ out, int n) {
    int t = blockIdx.x * blockDim.x + threadIdx.x;
    int i = t >> 6, f = t & 63;
    if (i >= n) return;
    bool act = (K == 64) || (f < K);
    int e0 = rp[i], e1 = rp[i + 1];
    float acc = act ? G[(size_t)i * K + f] : 0.0f;  // self loop
    for (int e = e0; e < e1; ++e) {
        int s = col[e];
        if (act) acc += G[(size_t)s * K + f];
    }
    if (act) {
        float v = dinv[i] * acc + b[f];
        if (RELU) v = fmaxf(v, 0.0f);
        out[(size_t)i * K + f] = v;
    }
}

// ---- hyper phase A: M[h] = Binv[h] * sum_e G[colH[e]] ---------------------

template <int K>
__global__ void k_hyp_gatherA(const int* __restrict__ rp, const int* __restrict__ colH,
                              const float* __restrict__ G, const float* __restrict__ Binv,
                              float* __restrict__ M, int nh) {
    int t = blockIdx.x * blockDim.x + threadIdx.x;
    int h = t >> 6, f = t & 63;
    if (h >= nh) return;
    bool act = (K == 64) || (f < K);
    int e0 = rp[h], e1 = rp[h + 1];
    float acc = 0.0f;
    for (int e = e0; e < e1; ++e) {
        int nd = colH[e];
        if (act) acc += G[(size_t)nd * K + f];
    }
    if (act) M[(size_t)h * K + f] = acc * Binv[h];
}

// ---- hyper phase B: out[i] = relu?(Dinv[i] * sum_e M[colN[e]] + b) --------

template <int K, bool RELU>
__global__ void k_hyp_gatherB(const int* __restrict__ rp, const int* __restrict__ colN,
                              const float* __restrict__ M, const float* __restrict__ Dinv,
                              const float* __restrict__ b, float* __restrict__ out, int n) {
    int t = blockIdx.x * blockDim.x + threadIdx.x;
    int i = t >> 6, f = t & 63;
    if (i >= n) return;
    bool act = (K == 64) || (f < K);
    int e0 = rp[i], e1 = rp[i + 1];
    float acc = 0.0f;
    for (int e = e0; e < e1; ++e) {
        int h = colN[e];
        if (act) acc += M[(size_t)h * K + f];
    }
    if (act) {
        float v = acc * Dinv[i] + b[f];
        if (RELU) v = fmaxf(v, 0.0f);
        out[(size_t)i * K + f] = v;
    }
}

// ---- branch attention (K = 64), one node per wave -------------------------

__global__ void k_attn(const float* __restrict__ X, const float* __restrict__ Xh,
                       const float* __restrict__ w, float* __restrict__ out, int n) {
    int t = blockIdx.x * blockDim.x + threadIdx.x;
    int node = t >> 6, lane = t & 63;
    if (node >= n) return;
    float xv = X[t], hv = Xh[t];
    float p0 = xv * w[2 * lane + 0];
    float p1 = hv * w[2 * lane + 1];
#pragma unroll
    for (int o = 32; o; o >>= 1) {
        p0 += __shfl_xor(p0, o, 64);
        p1 += __shfl_xor(p1, o, 64);
    }
    float m = fmaxf(p0, p1);
    float e0 = expf(p0 - m), e1 = expf(p1 - m);
    float inv = 1.0f / (e0 + e1);
    out[t] = (e0 * xv + e1 * hv) * inv;
}

// ---- branch attention (K = 40) + log_softmax ------------------------------

__global__ void k_attn_lsm(const float* __restrict__ X, const float* __restrict__ Xh,
                           const float* __restrict__ w, float* __restrict__ out, int n) {
    int t = blockIdx.x * blockDim.x + threadIdx.x;
    int node = t >> 6, lane = t & 63;
    if (node >= n) return;
    bool act = lane < C;
    int idx = node * C + lane;
    float xv = act ? X[idx] : 0.0f;
    float hv = act ? Xh[idx] : 0.0f;
    float p0 = act ? xv * w[2 * lane + 0] : 0.0f;
    float p1 = act ? hv * w[2 * lane + 1] : 0.0f;
#pragma unroll
    for (int o = 32; o; o >>= 1) {
        p0 += __shfl_xor(p0, o, 64);
        p1 += __shfl_xor(p1, o, 64);
    }
    float m = fmaxf(p0, p1);
    float e0 = expf(p0 - m), e1 = expf(p1 - m);
    float inv = 1.0f / (e0 + e1);
    float v = (e0 * xv + e1 * hv) * inv;

    float mv = act ? v : -1e30f;
#pragma unroll
    for (int o = 32; o; o >>= 1) mv = fmaxf(mv, __shfl_xor(mv, o, 64));
    float ex = act ? expf(v - mv) : 0.0f;
    float s = ex;
#pragma unroll
    for (int o = 32; o; o >>= 1) s += __shfl_xor(s, o, 64);
    float lse = mv + logf(s);
    if (act) out[idx] = v - lse;
}

}  // namespace

extern "C" void kernel_launch(void* const* d_in, const int* in_sizes, int n_in,
                              void* d_out, int out_size, void* d_ws, size_t ws_size,
                              hipStream_t stream) {
    const float* x     = (const float*)d_in[0];
    const int*   ei    = (const int*)d_in[1];
    const int*   esrc  = ei;
    const int*   edst  = ei + NE;
    const int*   hnode = (const int*)d_in[2];
    const int*   hid   = (const int*)d_in[3];
    const float* W1g = (const float*)d_in[4];
    const float* b1g = (const float*)d_in[5];
    const float* W1h = (const float*)d_in[6];
    const float* b1h = (const float*)d_in[7];
    const float* aw1 = (const float*)d_in[8];
    const float* W2g = (const float*)d_in[9];
    const float* b2g = (const float*)d_in[10];
    const float* W2h = (const float*)d_in[11];
    const float* b2h = (const float*)d_in[12];
    const float* aw2 = (const float*)d_in[13];
    float* out = (float*)d_out;

    char* ws = (char*)d_ws;
    size_t off = 0;
    auto alloc = [&](size_t bytes) -> void* {
        void* p = (void*)(ws + off);
        off = (off + bytes + 255) & ~(size_t)255;
        return p;
    };
    float* dinv = (float*)alloc((size_t)NN * 4);
    float* Binv = (float*)alloc((size_t)NH * 4);
    float* Dinv = (float*)alloc((size_t)NN * 4);
    // counts (reused as cursors): contiguous block for one-memset zeroing
    int* cntE = (int*)alloc((size_t)(NN + NH + NN) * 4);
    int* cntH = cntE + NN;
    int* cntN = cntH + NH;
    int* rpE  = (int*)alloc((size_t)(NN + 1) * 4);
    int* rpH  = (int*)alloc((size_t)(NH + 1) * 4);
    int* rpN  = (int*)alloc((size_t)(NN + 1) * 4);
    int* colE = (int*)alloc((size_t)NE * 4);
    int* colH = (int*)alloc((size_t)NI * 4);
    int* colN = (int*)alloc((size_t)NI * 4);
    int* bsum = (int*)alloc(256 * 4);
    float* A  = (float*)alloc((size_t)NN * D * 4);   // 25.6 MB
    float* Bb = (float*)alloc((size_t)NN * D * 4);
    float* Cc = (float*)alloc((size_t)NN * D * 4);
    float* M  = (float*)alloc((size_t)NH * D * 4);   // 2.56 MB

    const int B = 256;
    int gNN  = (NN + 255) / 256;
    int gNE  = (NE + 255) / 256;        // covers NI too (equal)
    int gN64 = NN * 64 / 256;           // 25000
    int gH64 = NH * 64 / 256;           // 2500
    int nbE  = (NN + 1 + 1023) / 1024;  // 98
    int nbH  = (NH + 1 + 1023) / 1024;  // 10

    size_t cntBytes = (size_t)(NN + NH + NN) * 4;

    // ---- build degrees + CSR (deterministic, rebuilt every call) ----
    hipMemsetAsync(cntE, 0, cntBytes, stream);
    k_count_all<<<gNE, B, 0, stream>>>(edst, hid, hnode, cntE, cntH, cntN);
    k_degs<<<gNN, B, 0, stream>>>(cntE, cntH, cntN, dinv, Binv, Dinv);

    k_scan_pass1<<<nbE, B, 0, stream>>>(cntE, NN + 1, bsum);
    k_scan_bsum<<<1, 64, 0, stream>>>(bsum, nbE);
    k_scan_pass3<<<nbE, B, 0, stream>>>(cntE, NN, bsum, rpE);

    k_scan_pass1<<<nbH, B, 0, stream>>>(cntH, NH + 1, bsum);
    k_scan_bsum<<<1, 64, 0, stream>>>(bsum, nbH);
    k_scan_pass3<<<nbH, B, 0, stream>>>(cntH, NH, bsum, rpH);

    k_scan_pass1<<<nbE, B, 0, stream>>>(cntN, NN + 1, bsum);
    k_scan_bsum<<<1, 64, 0, stream>>>(bsum, nbE);
    k_scan_pass3<<<nbE, B, 0, stream>>>(cntN, NN, bsum, rpN);

    hipMemsetAsync(cntE, 0, cntBytes, stream);  // reuse as cursors
    k_fill_all<<<gNE, B, 0, stream>>>(esrc, edst, hid, hnode, rpE, rpH, rpN,
                                      cntE, cntH, cntN, colE, colH, colN);

    // ---- layer 1 GCN: x1 = relu(dinv*(self + gather) + b1g) ----
    k_gemm<64, true><<<gNN, B, 0, stream>>>(x, W1g, dinv, A, NN);
    k_gcn_gather<64, true><<<gN64, B, 0, stream>>>(rpE, colE, A, dinv, b1g, Bb, NN);
    // Bb = x1

    // ---- layer 1 hypergraph on x1 ----
    k_gemm<64, false><<<gNN, B, 0, stream>>>(Bb, W1h, nullptr, A, NN);
    k_hyp_gatherA<64><<<gH64, B, 0, stream>>>(rpH, colH, A, Binv, M, NH);
    k_hyp_gatherB<64, true><<<gN64, B, 0, stream>>>(rpN, colN, M, Dinv, b1h, Cc, NN);
    // Cc = x_hyper

    // ---- attention 1: A = xa ----
    k_attn<<<gN64, B, 0, stream>>>(Bb, Cc, aw1, A, NN);

    // ---- layer 2 GCN on xa (K=40, no relu) ----
    k_gemm<40, true><<<gNN, B, 0, stream>>>(A, W2g, dinv, Bb, NN);
    k_gcn_gather<40, false><<<gN64, B, 0, stream>>>(rpE, colE, Bb, dinv, b2g, A, NN);
    // A = x2

    // ---- layer 2 hypergraph on x_hyper (K=40, no relu) ----
    k_gemm<40, false><<<gNN, B, 0, stream>>>(Cc, W2h, nullptr, Bb, NN);
    k_hyp_gatherA<40><<<gH64, B, 0, stream>>>(rpH, colH, Bb, Binv, M, NH);
    k_hyp_gatherB<40, false><<<gN64, B, 0, stream>>>(rpN, colN, M, Dinv, b2h, Cc, NN);
    // Cc = xh2

    // ---- attention 2 + log_softmax -> out ----
    k_attn_lsm<<<gN64, B, 0, stream>>>(A, Cc, aw2, out, NN);
}

// Round 3
// 1046.724 us; speedup vs baseline: 1.7940x; 1.1622x over previous
//
#include <hip/hip_runtime.h>
#include <math.h>

namespace {

constexpr int NN = 100000;   // nodes
constexpr int NE = 1200000;  // edges
constexpr int NH = 10000;    // hyperedges
constexpr int NI = 1200000;  // incidences
constexpr int D  = 64;       // hidden dim
constexpr int C  = 40;       // classes

constexpr int OFF_H = NN;         // hyperedge counts/rowptr offset
constexpr int OFF_N = NN + NH;    // node-incidence counts/rowptr offset
constexpr int NT    = NN + NH + NN;

using u16 = unsigned short;
using u32 = unsigned int;

__device__ __forceinline__ float bf2f(u16 u) {
    u32 v = (u32)u << 16;
    return __builtin_bit_cast(float, v);
}
__device__ __forceinline__ u16 f2bf(float f) {
    u32 u = __builtin_bit_cast(u32, f);
    return (u16)((u + 0x7FFFu + ((u >> 16) & 1u)) >> 16);
}

// ---- count + rank (rank = old count value) --------------------------------

__global__ void k_count_rank(const int* __restrict__ edst, const int* __restrict__ hid,
                             const int* __restrict__ hnode, int* __restrict__ cntAll,
                             int* __restrict__ rE, int* __restrict__ rH,
                             int* __restrict__ rN) {
    int t = blockIdx.x * blockDim.x + threadIdx.x;
    if (t < NE) rE[t] = atomicAdd(&cntAll[edst[t]], 1);
    if (t < NI) {
        rH[t] = atomicAdd(&cntAll[OFF_H + hid[t]], 1);
        rN[t] = atomicAdd(&cntAll[OFF_N + hnode[t]], 1);
    }
}

__global__ void k_degs(const int* __restrict__ cntAll, float* __restrict__ dinv,
                       float* __restrict__ Binv, float* __restrict__ Dinv) {
    int t = blockIdx.x * blockDim.x + threadIdx.x;
    if (t < NN) {
        dinv[t] = rsqrtf((float)cntAll[t] + 1.0f);  // +1 self loop
        int c = cntAll[OFF_N + t];
        Dinv[t] = c > 0 ? 1.0f / (float)c : 0.0f;
    }
    if (t < NH) {
        int c = cntAll[OFF_H + t];
        Binv[t] = c > 0 ? 1.0f / (float)c : 0.0f;
    }
}

// ---- exclusive prefix scan over cntAll[0..NT) -> rpAll[0..NT] -------------

__global__ void k_scan_pass1(const int* __restrict__ cnt, int n, int* __restrict__ bsum) {
    __shared__ int lds[4];
    int base = blockIdx.x * 1024;
    int s = 0;
    for (int i = threadIdx.x; i < 1024; i += 256) {
        int idx = base + i;
        s += (idx < n) ? cnt[idx] : 0;
    }
#pragma unroll
    for (int o = 32; o; o >>= 1) s += __shfl_xor(s, o, 64);
    if ((threadIdx.x & 63) == 0) lds[threadIdx.x >> 6] = s;
    __syncthreads();
    if (threadIdx.x == 0) bsum[blockIdx.x] = lds[0] + lds[1] + lds[2] + lds[3];
}

__global__ void k_scan_bsum(int* __restrict__ bsum, int nb) {
    int lane = threadIdx.x;  // single wave of 64
    int acc = 0;
    for (int base = 0; base < nb; base += 64) {
        int idx = base + lane;
        int v = (idx < nb) ? bsum[idx] : 0;
        int sc = v;
#pragma unroll
        for (int o = 1; o < 64; o <<= 1) {
            int t = __shfl_up(sc, o, 64);
            if (lane >= o) sc += t;
        }
        if (idx < nb) bsum[idx] = acc + sc - v;  // exclusive
        acc += __shfl(sc, 63, 64);
    }
}

__global__ void k_scan_pass3(const int* __restrict__ cnt, int n,
                             const int* __restrict__ bsum, int* __restrict__ rowptr) {
    __shared__ int warpsum[4];
    int lane = threadIdx.x & 63, wid = threadIdx.x >> 6;
    int base = blockIdx.x * 1024 + threadIdx.x * 4;
    int v[4];
    int s = 0;
#pragma unroll
    for (int j = 0; j < 4; ++j) {
        int idx = base + j;
        v[j] = (idx < n) ? cnt[idx] : 0;
        s += v[j];
    }
    int sc = s;
#pragma unroll
    for (int o = 1; o < 64; o <<= 1) {
        int t = __shfl_up(sc, o, 64);
        if (lane >= o) sc += t;
    }
    if (lane == 63) warpsum[wid] = sc;
    __syncthreads();
    int woff = 0;
    for (int w = 0; w < wid; ++w) woff += warpsum[w];
    int excl = bsum[blockIdx.x] + woff + (sc - s);
#pragma unroll
    for (int j = 0; j < 4; ++j) {
        int idx = base + j;
        if (idx <= n) rowptr[idx] = excl;
        excl += v[j];
    }
}

// ---- CSR fill: pure scattered stores (no atomics) -------------------------

__global__ void k_fill(const int* __restrict__ esrc, const int* __restrict__ edst,
                       const int* __restrict__ hid, const int* __restrict__ hnode,
                       const int* __restrict__ rpAll, const int* __restrict__ rE,
                       const int* __restrict__ rH, const int* __restrict__ rN,
                       int* __restrict__ colAll) {
    int t = blockIdx.x * blockDim.x + threadIdx.x;
    if (t < NE) colAll[rpAll[edst[t]] + rE[t]] = esrc[t];
    if (t < NI) {
        colAll[rpAll[OFF_H + hid[t]] + rH[t]] = hnode[t];
        colAll[rpAll[OFF_N + hnode[t]] + rN[t]] = hid[t];
    }
}

// ---- GEMM: Y[r][c] = (sum_k X[r][k] * W[k][c]) * scale?[r] -> bf16 --------

__device__ __forceinline__ u32 pack2(float a, float b) {
    return (u32)f2bf(a) | ((u32)f2bf(b) << 16);
}

template <int K, bool SCALE, bool INBF>
__global__ __launch_bounds__(256) void k_gemm(const void* __restrict__ Xv,
                                              const float* __restrict__ W,
                                              const float* __restrict__ scale,
                                              u16* __restrict__ Y, int n) {
    __shared__ float4 Wl[D * K / 4];
    for (int i = threadIdx.x; i < D * K / 4; i += 256)
        Wl[i] = reinterpret_cast<const float4*>(W)[i];
    __syncthreads();

    int r = blockIdx.x * 256 + threadIdx.x;
    if (r >= n) return;

    float xr[D];
    if (INBF) {
        const uint4* x4 = reinterpret_cast<const uint4*>((const u16*)Xv + (size_t)r * D);
#pragma unroll
        for (int i = 0; i < D / 8; ++i) {
            uint4 v = x4[i];
            u32 w0 = v.x, w1 = v.y, w2 = v.z, w3 = v.w;
            xr[8 * i + 0] = __builtin_bit_cast(float, w0 << 16);
            xr[8 * i + 1] = __builtin_bit_cast(float, w0 & 0xFFFF0000u);
            xr[8 * i + 2] = __builtin_bit_cast(float, w1 << 16);
            xr[8 * i + 3] = __builtin_bit_cast(float, w1 & 0xFFFF0000u);
            xr[8 * i + 4] = __builtin_bit_cast(float, w2 << 16);
            xr[8 * i + 5] = __builtin_bit_cast(float, w2 & 0xFFFF0000u);
            xr[8 * i + 6] = __builtin_bit_cast(float, w3 << 16);
            xr[8 * i + 7] = __builtin_bit_cast(float, w3 & 0xFFFF0000u);
        }
    } else {
        const float4* x4 = reinterpret_cast<const float4*>((const float*)Xv + (size_t)r * D);
#pragma unroll
        for (int i = 0; i < D / 4; ++i) {
            float4 v = x4[i];
            xr[4 * i + 0] = v.x; xr[4 * i + 1] = v.y;
            xr[4 * i + 2] = v.z; xr[4 * i + 3] = v.w;
        }
    }

    float acc[K];
#pragma unroll
    for (int c = 0; c < K; ++c) acc[c] = 0.0f;

#pragma unroll
    for (int k = 0; k < D; ++k) {
        float xv = xr[k];
#pragma unroll
        for (int c4 = 0; c4 < K / 4; ++c4) {
            float4 w = Wl[k * (K / 4) + c4];
            acc[4 * c4 + 0] = fmaf(xv, w.x, acc[4 * c4 + 0]);
            acc[4 * c4 + 1] = fmaf(xv, w.y, acc[4 * c4 + 1]);
            acc[4 * c4 + 2] = fmaf(xv, w.z, acc[4 * c4 + 2]);
            acc[4 * c4 + 3] = fmaf(xv, w.w, acc[4 * c4 + 3]);
        }
    }

    float s = SCALE ? scale[r] : 1.0f;
    uint4* y4 = reinterpret_cast<uint4*>(Y + (size_t)r * K);
#pragma unroll
    for (int j = 0; j < K / 8; ++j) {
        uint4 o;
        o.x = pack2(acc[8 * j + 0] * s, acc[8 * j + 1] * s);
        o.y = pack2(acc[8 * j + 2] * s, acc[8 * j + 3] * s);
        o.z = pack2(acc[8 * j + 4] * s, acc[8 * j + 5] * s);
        o.w = pack2(acc[8 * j + 6] * s, acc[8 * j + 7] * s);
        y4[j] = o;
    }
}

// ---- fused: xa = branch_attention(x1, xh, aw); Y = (xa @ W)*dinv -> bf16 --

__global__ __launch_bounds__(256) void k_gemm_attn(const u16* __restrict__ X1,
                                                   const u16* __restrict__ XH,
                                                   const float* __restrict__ aw,
                                                   const float* __restrict__ W,
                                                   const float* __restrict__ scale,
                                                   u16* __restrict__ Y, int n) {
    __shared__ float4 Wl[D * C / 4];
    __shared__ float awl[2 * D];
    for (int i = threadIdx.x; i < D * C / 4; i += 256)
        Wl[i] = reinterpret_cast<const float4*>(W)[i];
    for (int i = threadIdx.x; i < 2 * D; i += 256) awl[i] = aw[i];
    __syncthreads();

    int r = blockIdx.x * 256 + threadIdx.x;
    if (r >= n) return;

    float a[D], h[D];
    {
        const uint4* x4 = reinterpret_cast<const uint4*>(X1 + (size_t)r * D);
        const uint4* h4 = reinterpret_cast<const uint4*>(XH + (size_t)r * D);
#pragma unroll
        for (int i = 0; i < D / 8; ++i) {
            uint4 v = x4[i];
            a[8 * i + 0] = __builtin_bit_cast(float, v.x << 16);
            a[8 * i + 1] = __builtin_bit_cast(float, v.x & 0xFFFF0000u);
            a[8 * i + 2] = __builtin_bit_cast(float, v.y << 16);
            a[8 * i + 3] = __builtin_bit_cast(float, v.y & 0xFFFF0000u);
            a[8 * i + 4] = __builtin_bit_cast(float, v.z << 16);
            a[8 * i + 5] = __builtin_bit_cast(float, v.z & 0xFFFF0000u);
            a[8 * i + 6] = __builtin_bit_cast(float, v.w << 16);
            a[8 * i + 7] = __builtin_bit_cast(float, v.w & 0xFFFF0000u);
            uint4 u = h4[i];
            h[8 * i + 0] = __builtin_bit_cast(float, u.x << 16);
            h[8 * i + 1] = __builtin_bit_cast(float, u.x & 0xFFFF0000u);
            h[8 * i + 2] = __builtin_bit_cast(float, u.y << 16);
            h[8 * i + 3] = __builtin_bit_cast(float, u.y & 0xFFFF0000u);
            h[8 * i + 4] = __builtin_bit_cast(float, u.z << 16);
            h[8 * i + 5] = __builtin_bit_cast(float, u.z & 0xFFFF0000u);
            h[8 * i + 6] = __builtin_bit_cast(float, u.w << 16);
            h[8 * i + 7] = __builtin_bit_cast(float, u.w & 0xFFFF0000u);
        }
    }

    float s0 = 0.0f, s1 = 0.0f;
#pragma unroll
    for (int k = 0; k < D; ++k) {
        s0 = fmaf(a[k], awl[2 * k + 0], s0);
        s1 = fmaf(h[k], awl[2 * k + 1], s1);
    }
    float m = fmaxf(s0, s1);
    float e0 = expf(s0 - m), e1 = expf(s1 - m);
    float inv = 1.0f / (e0 + e1);
    float a0 = e0 * inv, a1 = e1 * inv;
#pragma unroll
    for (int k = 0; k < D; ++k) a[k] = a0 * a[k] + a1 * h[k];

    float acc[C];
#pragma unroll
    for (int c = 0; c < C; ++c) acc[c] = 0.0f;
#pragma unroll
    for (int k = 0; k < D; ++k) {
        float xv = a[k];
#pragma unroll
        for (int c4 = 0; c4 < C / 4; ++c4) {
            float4 w = Wl[k * (C / 4) + c4];
            acc[4 * c4 + 0] = fmaf(xv, w.x, acc[4 * c4 + 0]);
            acc[4 * c4 + 1] = fmaf(xv, w.y, acc[4 * c4 + 1]);
            acc[4 * c4 + 2] = fmaf(xv, w.z, acc[4 * c4 + 2]);
            acc[4 * c4 + 3] = fmaf(xv, w.w, acc[4 * c4 + 3]);
        }
    }
    float s = scale[r];
    uint4* y4 = reinterpret_cast<uint4*>(Y + (size_t)r * C);
#pragma unroll
    for (int j = 0; j < C / 8; ++j) {
        uint4 o;
        o.x = pack2(acc[8 * j + 0] * s, acc[8 * j + 1] * s);
        o.y = pack2(acc[8 * j + 2] * s, acc[8 * j + 3] * s);
        o.z = pack2(acc[8 * j + 4] * s, acc[8 * j + 5] * s);
        o.w = pack2(acc[8 * j + 6] * s, acc[8 * j + 7] * s);
        y4[j] = o;
    }
}

// ---- GCN gather+finalize (bf16 sources, f32 accumulate) -------------------

template <int K, bool RELU, bool OUTBF>
__global__ void k_gcn_gather(const int* __restrict__ rp, const int* __restrict__ col,
                             const u16* __restrict__ G, const float* __restrict__ dinv,
                             const float* __restrict__ b, void* __restrict__ out, int n) {
    int t = blockIdx.x * blockDim.x + threadIdx.x;
    int i = t >> 6, f = t & 63;
    if (i >= n) return;
    bool act = (K == 64) || (f < K);
    int e0 = rp[i], e1 = rp[i + 1];
    float acc = act ? bf2f(G[(size_t)i * K + f]) : 0.0f;  // self loop
    for (int e = e0; e < e1; ++e) {
        int s = col[e];
        if (act) acc += bf2f(G[(size_t)s * K + f]);
    }
    if (act) {
        float v = dinv[i] * acc + b[f];
        if (RELU) v = fmaxf(v, 0.0f);
        if (OUTBF) ((u16*)out)[(size_t)i * K + f] = f2bf(v);
        else       ((float*)out)[(size_t)i * K + f] = v;
    }
}

// ---- hyper phase A: M[h] = bf16(Binv[h] * sum_e G[col[e]]) ----------------

template <int K>
__global__ void k_hypA(const int* __restrict__ rp, const int* __restrict__ col,
                       const u16* __restrict__ G, const float* __restrict__ Binv,
                       u16* __restrict__ M, int nh) {
    int t = blockIdx.x * blockDim.x + threadIdx.x;
    int h = t >> 6, f = t & 63;
    if (h >= nh) return;
    bool act = (K == 64) || (f < K);
    int e0 = rp[h], e1 = rp[h + 1];
    float acc = 0.0f;
    for (int e = e0; e < e1; ++e) {
        int nd = col[e];
        if (act) acc += bf2f(G[(size_t)nd * K + f]);
    }
    if (act) M[(size_t)h * K + f] = f2bf(acc * Binv[h]);
}

// ---- hyper phase B: out[i] = relu?(Dinv[i] * sum_e M[col[e]] + b) ---------

template <int K, bool RELU, bool OUTBF>
__global__ void k_hypB(const int* __restrict__ rp, const int* __restrict__ col,
                       const u16* __restrict__ M, const float* __restrict__ Dinv,
                       const float* __restrict__ b, void* __restrict__ out, int n) {
    int t = blockIdx.x * blockDim.x + threadIdx.x;
    int i = t >> 6, f = t & 63;
    if (i >= n) return;
    bool act = (K == 64) || (f < K);
    int e0 = rp[i], e1 = rp[i + 1];
    float acc = 0.0f;
    for (int e = e0; e < e1; ++e) {
        int h = col[e];
        if (act) acc += bf2f(M[(size_t)h * K + f]);
    }
    if (act) {
        float v = acc * Dinv[i] + b[f];
        if (RELU) v = fmaxf(v, 0.0f);
        if (OUTBF) ((u16*)out)[(size_t)i * K + f] = f2bf(v);
        else       ((float*)out)[(size_t)i * K + f] = v;
    }
}

// ---- branch attention (K = 40) + log_softmax ------------------------------

__global__ void k_attn_lsm(const float* __restrict__ X, const float* __restrict__ Xh,
                           const float* __restrict__ w, float* __restrict__ out, int n) {
    int t = blockIdx.x * blockDim.x + threadIdx.x;
    int node = t >> 6, lane = t & 63;
    if (node >= n) return;
    bool act = lane < C;
    int idx = node * C + lane;
    float xv = act ? X[idx] : 0.0f;
    float hv = act ? Xh[idx] : 0.0f;
    float p0 = act ? xv * w[2 * lane + 0] : 0.0f;
    float p1 = act ? hv * w[2 * lane + 1] : 0.0f;
#pragma unroll
    for (int o = 32; o; o >>= 1) {
        p0 += __shfl_xor(p0, o, 64);
        p1 += __shfl_xor(p1, o, 64);
    }
    float m = fmaxf(p0, p1);
    float e0 = expf(p0 - m), e1 = expf(p1 - m);
    float inv = 1.0f / (e0 + e1);
    float v = (e0 * xv + e1 * hv) * inv;

    float mv = act ? v : -1e30f;
#pragma unroll
    for (int o = 32; o; o >>= 1) mv = fmaxf(mv, __shfl_xor(mv, o, 64));
    float ex = act ? expf(v - mv) : 0.0f;
    float s = ex;
#pragma unroll
    for (int o = 32; o; o >>= 1) s += __shfl_xor(s, o, 64);
    float lse = mv + logf(s);
    if (act) out[idx] = v - lse;
}

}  // namespace

extern "C" void kernel_launch(void* const* d_in, const int* in_sizes, int n_in,
                              void* d_out, int out_size, void* d_ws, size_t ws_size,
                              hipStream_t stream) {
    const float* x     = (const float*)d_in[0];
    const int*   ei    = (const int*)d_in[1];
    const int*   esrc  = ei;
    const int*   edst  = ei + NE;
    const int*   hnode = (const int*)d_in[2];
    const int*   hid   = (const int*)d_in[3];
    const float* W1g = (const float*)d_in[4];
    const float* b1g = (const float*)d_in[5];
    const float* W1h = (const float*)d_in[6];
    const float* b1h = (const float*)d_in[7];
    const float* aw1 = (const float*)d_in[8];
    const float* W2g = (const float*)d_in[9];
    const float* b2g = (const float*)d_in[10];
    const float* W2h = (const float*)d_in[11];
    const float* b2h = (const float*)d_in[12];
    const float* aw2 = (const float*)d_in[13];
    float* out = (float*)d_out;

    char* ws = (char*)d_ws;
    size_t off = 0;
    auto alloc = [&](size_t bytes) -> void* {
        void* p = (void*)(ws + off);
        off = (off + bytes + 255) & ~(size_t)255;
        return p;
    };
    float* dinv   = (float*)alloc((size_t)NN * 4);
    float* Binv   = (float*)alloc((size_t)NH * 4);
    float* Dinv   = (float*)alloc((size_t)NN * 4);
    int*   cntAll = (int*)alloc((size_t)NT * 4);
    int*   rpAll  = (int*)alloc((size_t)(NT + 1) * 4);
    int*   rE     = (int*)alloc((size_t)NE * 4);
    int*   rH     = (int*)alloc((size_t)NI * 4);
    int*   rN     = (int*)alloc((size_t)NI * 4);
    int*   colAll = (int*)alloc((size_t)(NE + 2 * (size_t)NI) * 4);
    int*   bsum   = (int*)alloc(256 * 4);
    u16*   A16    = (u16*)alloc((size_t)NN * D * 2);   // 12.8 MB
    u16*   X1     = (u16*)alloc((size_t)NN * D * 2);
    u16*   XH16   = (u16*)alloc((size_t)NN * D * 2);
    u16*   M16    = (u16*)alloc((size_t)NH * D * 2);   // 1.28 MB
    float* X2f    = (float*)alloc((size_t)NN * C * 4); // 16 MB
    float* XH2f   = (float*)alloc((size_t)NN * C * 4);

    const int B = 256;
    int gNN  = (NN + 255) / 256;
    int gNE  = (NE + 255) / 256;       // NE == NI
    int gN64 = NN * 64 / 256;          // 25000 blocks, 1 wave per node
    int gH64 = NH * 64 / 256;          // 2500
    int nbT  = (NT + 1023) / 1024;     // 206

    // ---- build degrees + unified CSR (rebuilt every call) ----
    hipMemsetAsync(cntAll, 0, (size_t)NT * 4, stream);
    k_count_rank<<<gNE, B, 0, stream>>>(edst, hid, hnode, cntAll, rE, rH, rN);
    k_degs<<<gNN, B, 0, stream>>>(cntAll, dinv, Binv, Dinv);

    k_scan_pass1<<<nbT, B, 0, stream>>>(cntAll, NT, bsum);
    k_scan_bsum<<<1, 64, 0, stream>>>(bsum, nbT);
    k_scan_pass3<<<nbT, B, 0, stream>>>(cntAll, NT, bsum, rpAll);

    k_fill<<<gNE, B, 0, stream>>>(esrc, edst, hid, hnode, rpAll, rE, rH, rN, colAll);

    // ---- layer 1 GCN: x1 = relu(dinv*(self + gather) + b1g) ----
    k_gemm<64, true, false><<<gNN, B, 0, stream>>>(x, W1g, dinv, A16, NN);
    k_gcn_gather<64, true, true><<<gN64, B, 0, stream>>>(rpAll, colAll, A16, dinv, b1g, X1, NN);

    // ---- layer 1 hypergraph on x1 ----
    k_gemm<64, false, true><<<gNN, B, 0, stream>>>(X1, W1h, nullptr, A16, NN);
    k_hypA<64><<<gH64, B, 0, stream>>>(rpAll + OFF_H, colAll, A16, Binv, M16, NH);
    k_hypB<64, true, true><<<gN64, B, 0, stream>>>(rpAll + OFF_N, colAll, M16, Dinv, b1h, XH16, NN);

    // ---- attn1 fused into layer-2 GCN GEMM: G2 = (attn(x1,xh)@W2g)*dinv ----
    k_gemm_attn<<<gNN, B, 0, stream>>>(X1, XH16, aw1, W2g, dinv, A16, NN);
    k_gcn_gather<40, false, false><<<gN64, B, 0, stream>>>(rpAll, colAll, A16, dinv, b2g, X2f, NN);

    // ---- layer 2 hypergraph on x_hyper ----
    k_gemm<40, false, true><<<gNN, B, 0, stream>>>(XH16, W2h, nullptr, X1, NN);  // reuse X1 as G4
    k_hypA<40><<<gH64, B, 0, stream>>>(rpAll + OFF_H, colAll, X1, Binv, M16, NH);
    k_hypB<40, false, false><<<gN64, B, 0, stream>>>(rpAll + OFF_N, colAll, M16, Dinv, b2h, XH2f, NN);

    // ---- attention 2 + log_softmax -> out ----
    k_attn_lsm<<<gN64, B, 0, stream>>>(X2f, XH2f, aw2, out, NN);
}

// Round 4
// 459.184 us; speedup vs baseline: 4.0894x; 2.2795x over previous
//
#include <hip/hip_runtime.h>
#include <math.h>

namespace {

constexpr int NN = 100000;   // nodes
constexpr int NE = 1200000;  // edges
constexpr int NH = 10000;    // hyperedges
constexpr int NI = 1200000;  // incidences
constexpr int D  = 64;       // hidden dim
constexpr int C  = 40;       // classes

constexpr int OFF_H = NN;         // hyperedge rowptr offset
constexpr int OFF_N = NN + NH;    // node-incidence rowptr offset
constexpr int NT    = NN + NH + NN;

// bucket sort params: rel0 = edges by dst, rel1 = incid by hyperedge, rel2 = incid by node
constexpr int NBLK   = 300;                 // partition blocks per relation
constexpr int CHUNK  = 4000;                // NI / NBLK
constexpr int NBUK1  = 196;                 // 100000 >> 9
constexpr int NBUK2  = 157;                 // 10000 >> 6
constexpr int NBUK3  = 196;
constexpr int NBUKT  = NBUK1 + NBUK2 + NBUK3;  // 549

using u16 = unsigned short;
using u32 = unsigned int;

__device__ __forceinline__ float bf2f(u16 u) {
    u32 v = (u32)u << 16;
    return __builtin_bit_cast(float, v);
}
__device__ __forceinline__ u16 f2bf(float f) {
    u32 u = __builtin_bit_cast(u32, f);
    return (u16)((u + 0x7FFFu + ((u >> 16) & 1u)) >> 16);
}
__device__ __forceinline__ u32 pack2(float a, float b) {
    return (u32)f2bf(a) | ((u32)f2bf(b) << 16);
}

// ---- P1: per-(relation,block) LDS histogram over coarse buckets -----------

__global__ __launch_bounds__(256) void k_p1(const int* __restrict__ edst,
                                            const int* __restrict__ hid,
                                            const int* __restrict__ hnode,
                                            int* __restrict__ hist_g) {
    int rel = blockIdx.x / NBLK, blk = blockIdx.x % NBLK;
    const int* keys = rel == 0 ? edst : (rel == 1 ? hid : hnode);
    int bukBase = rel == 0 ? 0 : (rel == 1 ? NBUK1 : NBUK1 + NBUK2);
    int nbuk    = rel == 1 ? NBUK2 : NBUK1;
    int shift   = rel == 1 ? 6 : 9;
    __shared__ int h[NBUK1];
    for (int i = threadIdx.x; i < nbuk; i += 256) h[i] = 0;
    __syncthreads();
    int start = blk * CHUNK, end = start + CHUNK;  // NI == NE, exact
    for (int i = start + threadIdx.x; i < end; i += 256)
        atomicAdd(&h[keys[i] >> shift], 1);
    __syncthreads();
    for (int i = threadIdx.x; i < nbuk; i += 256)
        hist_g[(bukBase + i) * NBLK + blk] = h[i];
}

// ---- S1: per-bucket exclusive scan over blocks ----------------------------

__global__ __launch_bounds__(64) void k_s1(const int* __restrict__ hist_g,
                                           int* __restrict__ off_g,
                                           int* __restrict__ totals) {
    int g = blockIdx.x, lane = threadIdx.x;
    int acc = 0;
    for (int base = 0; base < NBLK; base += 64) {
        int idx = base + lane;
        int v = idx < NBLK ? hist_g[g * NBLK + idx] : 0;
        int sc = v;
#pragma unroll
        for (int o = 1; o < 64; o <<= 1) {
            int t = __shfl_up(sc, o, 64);
            if (lane >= o) sc += t;
        }
        if (idx < NBLK) off_g[g * NBLK + idx] = acc + sc - v;
        acc += __shfl(sc, 63, 64);
    }
    if (lane == 0) totals[g] = acc;
}

// ---- S2: scan bucket totals -> bucketBase; also final rowptr entry --------

__global__ __launch_bounds__(64) void k_s2(const int* __restrict__ totals,
                                           int* __restrict__ bucketBase,
                                           int* __restrict__ rowptr) {
    int lane = threadIdx.x;
    int acc = 0;
    for (int base = 0; base < NBUKT; base += 64) {
        int idx = base + lane;
        int v = idx < NBUKT ? totals[idx] : 0;
        int sc = v;
#pragma unroll
        for (int o = 1; o < 64; o <<= 1) {
            int t = __shfl_up(sc, o, 64);
            if (lane >= o) sc += t;
        }
        if (idx < NBUKT) bucketBase[idx] = acc + sc - v;
        acc += __shfl(sc, 63, 64);
    }
    if (lane == 0) { bucketBase[NBUKT] = acc; rowptr[NT] = acc; }
}

// ---- P2: partition (key,val) pairs into bucket-sorted order ---------------

__global__ __launch_bounds__(256) void k_p2(const int* __restrict__ esrc,
                                            const int* __restrict__ edst,
                                            const int* __restrict__ hid,
                                            const int* __restrict__ hnode,
                                            const int* __restrict__ off_g,
                                            const int* __restrict__ bucketBase,
                                            uint2* __restrict__ pairs) {
    int rel = blockIdx.x / NBLK, blk = blockIdx.x % NBLK;
    const int *keys, *vals;
    if (rel == 0)      { keys = edst;  vals = esrc;  }
    else if (rel == 1) { keys = hid;   vals = hnode; }
    else               { keys = hnode; vals = hid;   }
    int bukBase = rel == 0 ? 0 : (rel == 1 ? NBUK1 : NBUK1 + NBUK2);
    int nbuk    = rel == 1 ? NBUK2 : NBUK1;
    int shift   = rel == 1 ? 6 : 9;
    __shared__ int cur[NBUK1];
    for (int i = threadIdx.x; i < nbuk; i += 256) {
        int g = bukBase + i;
        cur[i] = bucketBase[g] + off_g[g * NBLK + blk];
    }
    __syncthreads();
    int start = blk * CHUNK, end = start + CHUNK;
    for (int i = start + threadIdx.x; i < end; i += 256) {
        int k = keys[i];
        int p = atomicAdd(&cur[k >> shift], 1);
        pairs[p] = make_uint2((u32)k, (u32)vals[i]);
    }
}

// ---- P3: per-bucket fine counting sort -> rowptr + colAll -----------------

__global__ __launch_bounds__(256) void k_p3(const uint2* __restrict__ pairs,
                                            const int* __restrict__ bucketBase,
                                            int* __restrict__ rowptr,
                                            int* __restrict__ colAll) {
    int g = blockIdx.x;
    int rel, lb;
    if (g < NBUK1)              { rel = 0; lb = g; }
    else if (g < NBUK1 + NBUK2) { rel = 1; lb = g - NBUK1; }
    else                        { rel = 2; lb = g - NBUK1 - NBUK2; }
    int shift   = rel == 1 ? 6 : 9;
    int bpb     = rel == 1 ? 64 : 512;
    int binBase = rel == 0 ? 0 : (rel == 1 ? NN : NN + NH);
    int nbins   = rel == 1 ? NH : NN;
    int keyBase = lb << shift;
    int e0 = bucketBase[g], e1 = bucketBase[g + 1];

    __shared__ int h[512];
    __shared__ int cur[512];
    __shared__ int wsum[4];
    int tid = threadIdx.x;
    for (int i = tid; i < 512; i += 256) h[i] = 0;
    __syncthreads();
    for (int i = e0 + tid; i < e1; i += 256)
        atomicAdd(&h[(int)pairs[i].x - keyBase], 1);
    __syncthreads();

    // block exclusive scan over h[0..512) -> cur
    int j0 = 2 * tid;
    int v0 = h[j0], v1 = h[j0 + 1];
    int s = v0 + v1;
    int lane = tid & 63, wid = tid >> 6;
    int sc = s;
#pragma unroll
    for (int o = 1; o < 64; o <<= 1) {
        int t = __shfl_up(sc, o, 64);
        if (lane >= o) sc += t;
    }
    if (lane == 63) wsum[wid] = sc;
    __syncthreads();
    int woff = 0;
    for (int w = 0; w < wid; ++w) woff += wsum[w];
    int excl = woff + sc - s;
    cur[j0] = excl;
    cur[j0 + 1] = excl + v0;
    __syncthreads();

    // rowptr for this bucket's bins
    for (int i = tid; i < bpb; i += 256) {
        int bin = keyBase + i;
        if (bin < nbins) rowptr[binBase + bin] = e0 + cur[i];
    }
    __syncthreads();

    // scatter values into final CSR positions
    for (int i = e0 + tid; i < e1; i += 256) {
        uint2 p = pairs[i];
        int pos = atomicAdd(&cur[(int)p.x - keyBase], 1);
        colAll[e0 + pos] = (int)p.y;
    }
}

// ---- degrees from rowptr diffs --------------------------------------------

__global__ void k_degs(const int* __restrict__ rp, float* __restrict__ dinv,
                       float* __restrict__ Binv, float* __restrict__ Dinv) {
    int t = blockIdx.x * blockDim.x + threadIdx.x;
    if (t < NN) {
        dinv[t] = rsqrtf((float)(rp[t + 1] - rp[t]) + 1.0f);  // +1 self loop
        int c = rp[OFF_N + t + 1] - rp[OFF_N + t];
        Dinv[t] = c > 0 ? 1.0f / (float)c : 0.0f;
    }
    if (t < NH) {
        int c = rp[OFF_H + t + 1] - rp[OFF_H + t];
        Binv[t] = c > 0 ? 1.0f / (float)c : 0.0f;
    }
}

// ---- GEMM: Y[r][c] = (sum_k X[r][k] * W[k][c]) * scale?[r] -> bf16 --------

template <int K, bool SCALE, bool INBF>
__global__ __launch_bounds__(256) void k_gemm(const void* __restrict__ Xv,
                                              const float* __restrict__ W,
                                              const float* __restrict__ scale,
                                              u16* __restrict__ Y, int n) {
    __shared__ float4 Wl[D * K / 4];
    for (int i = threadIdx.x; i < D * K / 4; i += 256)
        Wl[i] = reinterpret_cast<const float4*>(W)[i];
    __syncthreads();

    int r = blockIdx.x * 256 + threadIdx.x;
    if (r >= n) return;

    float xr[D];
    if (INBF) {
        const uint4* x4 = reinterpret_cast<const uint4*>((const u16*)Xv + (size_t)r * D);
#pragma unroll
        for (int i = 0; i < D / 8; ++i) {
            uint4 v = x4[i];
            xr[8 * i + 0] = __builtin_bit_cast(float, v.x << 16);
            xr[8 * i + 1] = __builtin_bit_cast(float, v.x & 0xFFFF0000u);
            xr[8 * i + 2] = __builtin_bit_cast(float, v.y << 16);
            xr[8 * i + 3] = __builtin_bit_cast(float, v.y & 0xFFFF0000u);
            xr[8 * i + 4] = __builtin_bit_cast(float, v.z << 16);
            xr[8 * i + 5] = __builtin_bit_cast(float, v.z & 0xFFFF0000u);
            xr[8 * i + 6] = __builtin_bit_cast(float, v.w << 16);
            xr[8 * i + 7] = __builtin_bit_cast(float, v.w & 0xFFFF0000u);
        }
    } else {
        const float4* x4 = reinterpret_cast<const float4*>((const float*)Xv + (size_t)r * D);
#pragma unroll
        for (int i = 0; i < D / 4; ++i) {
            float4 v = x4[i];
            xr[4 * i + 0] = v.x; xr[4 * i + 1] = v.y;
            xr[4 * i + 2] = v.z; xr[4 * i + 3] = v.w;
        }
    }

    float acc[K];
#pragma unroll
    for (int c = 0; c < K; ++c) acc[c] = 0.0f;

#pragma unroll
    for (int k = 0; k < D; ++k) {
        float xv = xr[k];
#pragma unroll
        for (int c4 = 0; c4 < K / 4; ++c4) {
            float4 w = Wl[k * (K / 4) + c4];
            acc[4 * c4 + 0] = fmaf(xv, w.x, acc[4 * c4 + 0]);
            acc[4 * c4 + 1] = fmaf(xv, w.y, acc[4 * c4 + 1]);
            acc[4 * c4 + 2] = fmaf(xv, w.z, acc[4 * c4 + 2]);
            acc[4 * c4 + 3] = fmaf(xv, w.w, acc[4 * c4 + 3]);
        }
    }

    float s = SCALE ? scale[r] : 1.0f;
    uint4* y4 = reinterpret_cast<uint4*>(Y + (size_t)r * K);
#pragma unroll
    for (int j = 0; j < K / 8; ++j) {
        uint4 o;
        o.x = pack2(acc[8 * j + 0] * s, acc[8 * j + 1] * s);
        o.y = pack2(acc[8 * j + 2] * s, acc[8 * j + 3] * s);
        o.z = pack2(acc[8 * j + 4] * s, acc[8 * j + 5] * s);
        o.w = pack2(acc[8 * j + 6] * s, acc[8 * j + 7] * s);
        y4[j] = o;
    }
}

// ---- fused: xa = branch_attention(x1, xh, aw); Y = (xa @ W)*dinv -> bf16 --

__global__ __launch_bounds__(256) void k_gemm_attn(const u16* __restrict__ X1,
                                                   const u16* __restrict__ XH,
                                                   const float* __restrict__ aw,
                                                   const float* __restrict__ W,
                                                   const float* __restrict__ scale,
                                                   u16* __restrict__ Y, int n) {
    __shared__ float4 Wl[D * C / 4];
    __shared__ float awl[2 * D];
    for (int i = threadIdx.x; i < D * C / 4; i += 256)
        Wl[i] = reinterpret_cast<const float4*>(W)[i];
    for (int i = threadIdx.x; i < 2 * D; i += 256) awl[i] = aw[i];
    __syncthreads();

    int r = blockIdx.x * 256 + threadIdx.x;
    if (r >= n) return;

    float a[D], h[D];
    {
        const uint4* x4 = reinterpret_cast<const uint4*>(X1 + (size_t)r * D);
        const uint4* h4 = reinterpret_cast<const uint4*>(XH + (size_t)r * D);
#pragma unroll
        for (int i = 0; i < D / 8; ++i) {
            uint4 v = x4[i];
            a[8 * i + 0] = __builtin_bit_cast(float, v.x << 16);
            a[8 * i + 1] = __builtin_bit_cast(float, v.x & 0xFFFF0000u);
            a[8 * i + 2] = __builtin_bit_cast(float, v.y << 16);
            a[8 * i + 3] = __builtin_bit_cast(float, v.y & 0xFFFF0000u);
            a[8 * i + 4] = __builtin_bit_cast(float, v.z << 16);
            a[8 * i + 5] = __builtin_bit_cast(float, v.z & 0xFFFF0000u);
            a[8 * i + 6] = __builtin_bit_cast(float, v.w << 16);
            a[8 * i + 7] = __builtin_bit_cast(float, v.w & 0xFFFF0000u);
            uint4 u = h4[i];
            h[8 * i + 0] = __builtin_bit_cast(float, u.x << 16);
            h[8 * i + 1] = __builtin_bit_cast(float, u.x & 0xFFFF0000u);
            h[8 * i + 2] = __builtin_bit_cast(float, u.y << 16);
            h[8 * i + 3] = __builtin_bit_cast(float, u.y & 0xFFFF0000u);
            h[8 * i + 4] = __builtin_bit_cast(float, u.z << 16);
            h[8 * i + 5] = __builtin_bit_cast(float, u.z & 0xFFFF0000u);
            h[8 * i + 6] = __builtin_bit_cast(float, u.w << 16);
            h[8 * i + 7] = __builtin_bit_cast(float, u.w & 0xFFFF0000u);
        }
    }

    float s0 = 0.0f, s1 = 0.0f;
#pragma unroll
    for (int k = 0; k < D; ++k) {
        s0 = fmaf(a[k], awl[2 * k + 0], s0);
        s1 = fmaf(h[k], awl[2 * k + 1], s1);
    }
    float m = fmaxf(s0, s1);
    float e0 = expf(s0 - m), e1 = expf(s1 - m);
    float inv = 1.0f / (e0 + e1);
    float a0 = e0 * inv, a1 = e1 * inv;
#pragma unroll
    for (int k = 0; k < D; ++k) a[k] = a0 * a[k] + a1 * h[k];

    float acc[C];
#pragma unroll
    for (int c = 0; c < C; ++c) acc[c] = 0.0f;
#pragma unroll
    for (int k = 0; k < D; ++k) {
        float xv = a[k];
#pragma unroll
        for (int c4 = 0; c4 < C / 4; ++c4) {
            float4 w = Wl[k * (C / 4) + c4];
            acc[4 * c4 + 0] = fmaf(xv, w.x, acc[4 * c4 + 0]);
            acc[4 * c4 + 1] = fmaf(xv, w.y, acc[4 * c4 + 1]);
            acc[4 * c4 + 2] = fmaf(xv, w.z, acc[4 * c4 + 2]);
            acc[4 * c4 + 3] = fmaf(xv, w.w, acc[4 * c4 + 3]);
        }
    }
    float s = scale[r];
    uint4* y4 = reinterpret_cast<uint4*>(Y + (size_t)r * C);
#pragma unroll
    for (int j = 0; j < C / 8; ++j) {
        uint4 o;
        o.x = pack2(acc[8 * j + 0] * s, acc[8 * j + 1] * s);
        o.y = pack2(acc[8 * j + 2] * s, acc[8 * j + 3] * s);
        o.z = pack2(acc[8 * j + 4] * s, acc[8 * j + 5] * s);
        o.w = pack2(acc[8 * j + 6] * s, acc[8 * j + 7] * s);
        y4[j] = o;
    }
}

// ---- GCN gather+finalize (bf16 sources, f32 acc, 4x unrolled) -------------

template <int K, bool RELU, bool OUTBF>
__global__ void k_gcn_gather(const int* __restrict__ rp, const int* __restrict__ col,
                             const u16* __restrict__ G, const float* __restrict__ dinv,
                             const float* __restrict__ b, void* __restrict__ out, int n) {
    int t = blockIdx.x * blockDim.x + threadIdx.x;
    int i = t >> 6, f = t & 63;
    if (i >= n) return;
    int e0 = __builtin_amdgcn_readfirstlane(rp[i]);
    int e1 = __builtin_amdgcn_readfirstlane(rp[i + 1]);
    float a0 = bf2f(G[(size_t)i * K + f]);  // self loop
    float a1 = 0.f, a2 = 0.f, a3 = 0.f;
    int e = e0;
    for (; e + 4 <= e1; e += 4) {
        int s0 = col[e], s1 = col[e + 1], s2 = col[e + 2], s3 = col[e + 3];
        a0 += bf2f(G[(size_t)s0 * K + f]);
        a1 += bf2f(G[(size_t)s1 * K + f]);
        a2 += bf2f(G[(size_t)s2 * K + f]);
        a3 += bf2f(G[(size_t)s3 * K + f]);
    }
    for (; e < e1; ++e) a0 += bf2f(G[(size_t)col[e] * K + f]);
    if ((K == 64) || (f < K)) {
        float v = dinv[i] * ((a0 + a1) + (a2 + a3)) + b[f];
        if (RELU) v = fmaxf(v, 0.0f);
        if (OUTBF) ((u16*)out)[(size_t)i * K + f] = f2bf(v);
        else       ((float*)out)[(size_t)i * K + f] = v;
    }
}

// ---- hyper phase A: M[h] = bf16(Binv[h] * sum_e G[col[e]]) ----------------

template <int K>
__global__ void k_hypA(const int* __restrict__ rp, const int* __restrict__ col,
                       const u16* __restrict__ G, const float* __restrict__ Binv,
                       u16* __restrict__ M, int nh) {
    int t = blockIdx.x * blockDim.x + threadIdx.x;
    int i = t >> 6, f = t & 63;
    if (i >= nh) return;
    int e0 = __builtin_amdgcn_readfirstlane(rp[i]);
    int e1 = __builtin_amdgcn_readfirstlane(rp[i + 1]);
    float a0 = 0.f, a1 = 0.f, a2 = 0.f, a3 = 0.f;
    int e = e0;
    for (; e + 4 <= e1; e += 4) {
        int s0 = col[e], s1 = col[e + 1], s2 = col[e + 2], s3 = col[e + 3];
        a0 += bf2f(G[(size_t)s0 * K + f]);
        a1 += bf2f(G[(size_t)s1 * K + f]);
        a2 += bf2f(G[(size_t)s2 * K + f]);
        a3 += bf2f(G[(size_t)s3 * K + f]);
    }
    for (; e < e1; ++e) a0 += bf2f(G[(size_t)col[e] * K + f]);
    if ((K == 64) || (f < K))
        M[(size_t)i * K + f] = f2bf(((a0 + a1) + (a2 + a3)) * Binv[i]);
}

// ---- hyper phase B: out[i] = relu?(Dinv[i] * sum_e M[col[e]] + b) ---------

template <int K, bool RELU, bool OUTBF>
__global__ void k_hypB(const int* __restrict__ rp, const int* __restrict__ col,
                       const u16* __restrict__ M, const float* __restrict__ Dinv,
                       const float* __restrict__ b, void* __restrict__ out, int n) {
    int t = blockIdx.x * blockDim.x + threadIdx.x;
    int i = t >> 6, f = t & 63;
    if (i >= n) return;
    int e0 = __builtin_amdgcn_readfirstlane(rp[i]);
    int e1 = __builtin_amdgcn_readfirstlane(rp[i + 1]);
    float a0 = 0.f, a1 = 0.f, a2 = 0.f, a3 = 0.f;
    int e = e0;
    for (; e + 4 <= e1; e += 4) {
        int s0 = col[e], s1 = col[e + 1], s2 = col[e + 2], s3 = col[e + 3];
        a0 += bf2f(M[(size_t)s0 * K + f]);
        a1 += bf2f(M[(size_t)s1 * K + f]);
        a2 += bf2f(M[(size_t)s2 * K + f]);
        a3 += bf2f(M[(size_t)s3 * K + f]);
    }
    for (; e < e1; ++e) a0 += bf2f(M[(size_t)col[e] * K + f]);
    if ((K == 64) || (f < K)) {
        float v = ((a0 + a1) + (a2 + a3)) * Dinv[i] + b[f];
        if (RELU) v = fmaxf(v, 0.0f);
        if (OUTBF) ((u16*)out)[(size_t)i * K + f] = f2bf(v);
        else       ((float*)out)[(size_t)i * K + f] = v;
    }
}

// ---- branch attention (K = 40) + log_softmax ------------------------------

__global__ void k_attn_lsm(const float* __restrict__ X, const float* __restrict__ Xh,
                           const float* __restrict__ w, float* __restrict__ out, int n) {
    int t = blockIdx.x * blockDim.x + threadIdx.x;
    int node = t >> 6, lane = t & 63;
    if (node >= n) return;
    bool act = lane < C;
    int idx = node * C + lane;
    float xv = act ? X[idx] : 0.0f;
    float hv = act ? Xh[idx] : 0.0f;
    float p0 = act ? xv * w[2 * lane + 0] : 0.0f;
    float p1 = act ? hv * w[2 * lane + 1] : 0.0f;
#pragma unroll
    for (int o = 32; o; o >>= 1) {
        p0 += __shfl_xor(p0, o, 64);
        p1 += __shfl_xor(p1, o, 64);
    }
    float m = fmaxf(p0, p1);
    float e0 = expf(p0 - m), e1 = expf(p1 - m);
    float inv = 1.0f / (e0 + e1);
    float v = (e0 * xv + e1 * hv) * inv;

    float mv = act ? v : -1e30f;
#pragma unroll
    for (int o = 32; o; o >>= 1) mv = fmaxf(mv, __shfl_xor(mv, o, 64));
    float ex = act ? expf(v - mv) : 0.0f;
    float s = ex;
#pragma unroll
    for (int o = 32; o; o >>= 1) s += __shfl_xor(s, o, 64);
    float lse = mv + logf(s);
    if (act) out[idx] = v - lse;
}

}  // namespace

extern "C" void kernel_launch(void* const* d_in, const int* in_sizes, int n_in,
                              void* d_out, int out_size, void* d_ws, size_t ws_size,
                              hipStream_t stream) {
    const float* x     = (const float*)d_in[0];
    const int*   ei    = (const int*)d_in[1];
    const int*   esrc  = ei;
    const int*   edst  = ei + NE;
    const int*   hnode = (const int*)d_in[2];
    const int*   hid   = (const int*)d_in[3];
    const float* W1g = (const float*)d_in[4];
    const float* b1g = (const float*)d_in[5];
    const float* W1h = (const float*)d_in[6];
    const float* b1h = (const float*)d_in[7];
    const float* aw1 = (const float*)d_in[8];
    const float* W2g = (const float*)d_in[9];
    const float* b2g = (const float*)d_in[10];
    const float* W2h = (const float*)d_in[11];
    const float* b2h = (const float*)d_in[12];
    const float* aw2 = (const float*)d_in[13];
    float* out = (float*)d_out;

    char* ws = (char*)d_ws;
    size_t off = 0;
    auto alloc = [&](size_t bytes) -> void* {
        void* p = (void*)(ws + off);
        off = (off + bytes + 255) & ~(size_t)255;
        return p;
    };
    float* dinv   = (float*)alloc((size_t)NN * 4);
    float* Binv   = (float*)alloc((size_t)NH * 4);
    float* Dinv   = (float*)alloc((size_t)NN * 4);
    int*   rpAll  = (int*)alloc((size_t)(NT + 1) * 4);
    int*   colAll = (int*)alloc((size_t)(NE + 2 * (size_t)NI) * 4);  // 14.4 MB
    int*   hist_g = (int*)alloc((size_t)NBUKT * NBLK * 4);           // 0.66 MB
    int*   off_g  = (int*)alloc((size_t)NBUKT * NBLK * 4);
    int*   totals = (int*)alloc((size_t)NBUKT * 4);
    int*   bukB   = (int*)alloc((size_t)(NBUKT + 1) * 4);
    // union region: pairs (28.8 MB, build-time) / A16,X1,XH16 (38.4 MB, compute-time)
    char*  U      = (char*)alloc((size_t)3 * NN * D * 2);
    uint2* pairs  = (uint2*)U;
    u16*   A16    = (u16*)U;
    u16*   X1     = (u16*)(U + (size_t)NN * D * 2);
    u16*   XH16   = (u16*)(U + (size_t)2 * NN * D * 2);
    u16*   M16    = (u16*)alloc((size_t)NH * D * 2);
    float* X2f    = (float*)alloc((size_t)NN * C * 4);
    float* XH2f   = (float*)alloc((size_t)NN * C * 4);

    const int B = 256;
    int gNN  = (NN + 255) / 256;
    int gN64 = NN * 64 / 256;          // 25000 blocks, 1 wave per node
    int gH64 = NH * 64 / 256;          // 2500

    // ---- build CSR + degrees via bucketed LDS counting sort ----
    k_p1<<<3 * NBLK, B, 0, stream>>>(edst, hid, hnode, hist_g);
    k_s1<<<NBUKT, 64, 0, stream>>>(hist_g, off_g, totals);
    k_s2<<<1, 64, 0, stream>>>(totals, bukB, rpAll);
    k_p2<<<3 * NBLK, B, 0, stream>>>(esrc, edst, hid, hnode, off_g, bukB, pairs);
    k_p3<<<NBUKT, B, 0, stream>>>(pairs, bukB, rpAll, colAll);
    k_degs<<<gNN, B, 0, stream>>>(rpAll, dinv, Binv, Dinv);

    // ---- layer 1 GCN: x1 = relu(dinv*(self + gather) + b1g) ----
    k_gemm<64, true, false><<<gNN, B, 0, stream>>>(x, W1g, dinv, A16, NN);
    k_gcn_gather<64, true, true><<<gN64, B, 0, stream>>>(rpAll, colAll, A16, dinv, b1g, X1, NN);

    // ---- layer 1 hypergraph on x1 ----
    k_gemm<64, false, true><<<gNN, B, 0, stream>>>(X1, W1h, nullptr, A16, NN);
    k_hypA<64><<<gH64, B, 0, stream>>>(rpAll + OFF_H, colAll, A16, Binv, M16, NH);
    k_hypB<64, true, true><<<gN64, B, 0, stream>>>(rpAll + OFF_N, colAll, M16, Dinv, b1h, XH16, NN);

    // ---- attn1 fused into layer-2 GCN GEMM: G2 = (attn(x1,xh)@W2g)*dinv ----
    k_gemm_attn<<<gNN, B, 0, stream>>>(X1, XH16, aw1, W2g, dinv, A16, NN);
    k_gcn_gather<40, false, false><<<gN64, B, 0, stream>>>(rpAll, colAll, A16, dinv, b2g, X2f, NN);

    // ---- layer 2 hypergraph on x_hyper ----
    k_gemm<40, false, true><<<gNN, B, 0, stream>>>(XH16, W2h, nullptr, X1, NN);  // X1 = G4
    k_hypA<40><<<gH64, B, 0, stream>>>(rpAll + OFF_H, colAll, X1, Binv, M16, NH);
    k_hypB<40, false, false><<<gN64, B, 0, stream>>>(rpAll + OFF_N, colAll, M16, Dinv, b2h, XH2f, NN);

    // ---- attention 2 + log_softmax -> out ----
    k_attn_lsm<<<gN64, B, 0, stream>>>(X2f, XH2f, aw2, out, NN);
}

// Round 5
// 433.127 us; speedup vs baseline: 4.3354x; 1.0602x over previous
//
#include <hip/hip_runtime.h>
#include <math.h>

namespace {

constexpr int NN = 100000;   // nodes
constexpr int NE = 1200000;  // edges
constexpr int NH = 10000;    // hyperedges
constexpr int NI = 1200000;  // incidences
constexpr int D  = 64;       // hidden dim
constexpr int C  = 40;       // classes

constexpr int OFF_H = NN;         // hyperedge rowptr offset
constexpr int OFF_N = NN + NH;    // node-incidence rowptr offset
constexpr int NT    = NN + NH + NN;

// bucket sort: rel0 = edges by dst, rel1 = incid by hyperedge, rel2 = incid by node
constexpr int NBLK   = 300;                 // partition blocks per relation
constexpr int CHUNK  = 4000;                // NI / NBLK
constexpr int NBUK1  = 196;                 // ceil(100000 / 512)
constexpr int NBUK2  = 157;                 // ceil(10000 / 64)
constexpr int NBUK3  = 196;
constexpr int NBUKT  = NBUK1 + NBUK2 + NBUK3;  // 549
constexpr int CAP    = 10240;               // slack region per bucket (mean ~6-7.7K)

using u16 = unsigned short;
using u32 = unsigned int;

__device__ __forceinline__ float bf2f(u16 u) {
    u32 v = (u32)u << 16;
    return __builtin_bit_cast(float, v);
}
__device__ __forceinline__ u16 f2bf(float f) {
    u32 u = __builtin_bit_cast(u32, f);
    return (u16)((u + 0x7FFFu + ((u >> 16) & 1u)) >> 16);
}
__device__ __forceinline__ u32 pack2(float a, float b) {
    return (u32)f2bf(a) | ((u32)f2bf(b) << 16);
}

// ---- BUILD: per-block LDS hist -> global cursor reserve -> packed scatter --

__global__ __launch_bounds__(256) void k_build(const int* __restrict__ esrc,
                                               const int* __restrict__ edst,
                                               const int* __restrict__ hid,
                                               const int* __restrict__ hnode,
                                               int* __restrict__ gcur,
                                               u32* __restrict__ pairs) {
    int rel = blockIdx.x / NBLK, blk = blockIdx.x % NBLK;
    const int *keys, *vals;
    if (rel == 0)      { keys = edst;  vals = esrc;  }
    else if (rel == 1) { keys = hid;   vals = hnode; }
    else               { keys = hnode; vals = hid;   }
    int bukBase = rel == 0 ? 0 : (rel == 1 ? NBUK1 : NBUK1 + NBUK2);
    int nbuk    = rel == 1 ? NBUK2 : NBUK1;
    int shift   = rel == 1 ? 6 : 9;
    int mask    = (1 << shift) - 1;

    __shared__ int h[NBUK1];
    __shared__ int cur[NBUK1];
    for (int i = threadIdx.x; i < nbuk; i += 256) h[i] = 0;
    __syncthreads();
    int start = blk * CHUNK, end = start + CHUNK;  // exact: NI == NBLK*CHUNK
    for (int i = start + threadIdx.x; i < end; i += 256)
        atomicAdd(&h[keys[i] >> shift], 1);
    __syncthreads();
    for (int i = threadIdx.x; i < nbuk; i += 256)
        cur[i] = atomicAdd(&gcur[bukBase + i], h[i]);
    __syncthreads();
    for (int i = start + threadIdx.x; i < end; i += 256) {
        int k = keys[i];
        int buk = k >> shift;
        int pos = atomicAdd(&cur[buk], 1);
        if (pos < CAP)
            pairs[(size_t)(bukBase + buk) * CAP + pos] =
                ((u32)(k & mask) << 17) | (u32)vals[i];
    }
}

// ---- S2: scan bucket totals -> bucketBase; also final rowptr entry --------

__global__ __launch_bounds__(64) void k_s2(const int* __restrict__ totals,
                                           int* __restrict__ bucketBase,
                                           int* __restrict__ rowptr) {
    int lane = threadIdx.x;
    int acc = 0;
    for (int base = 0; base < NBUKT; base += 64) {
        int idx = base + lane;
        int v = idx < NBUKT ? totals[idx] : 0;
        int sc = v;
#pragma unroll
        for (int o = 1; o < 64; o <<= 1) {
            int t = __shfl_up(sc, o, 64);
            if (lane >= o) sc += t;
        }
        if (idx < NBUKT) bucketBase[idx] = acc + sc - v;
        acc += __shfl(sc, 63, 64);
    }
    if (lane == 0) { bucketBase[NBUKT] = acc; rowptr[NT] = acc; }
}

// ---- P3: per-bucket fine counting sort -> rowptr + colAll + degrees -------

__global__ __launch_bounds__(256) void k_p3(const u32* __restrict__ pairs,
                                            const int* __restrict__ totals,
                                            const int* __restrict__ bucketBase,
                                            int* __restrict__ rowptr,
                                            int* __restrict__ colAll,
                                            float* __restrict__ dinv,
                                            float* __restrict__ Binv,
                                            float* __restrict__ Dinv) {
    int g = blockIdx.x;
    int rel, lb;
    if (g < NBUK1)              { rel = 0; lb = g; }
    else if (g < NBUK1 + NBUK2) { rel = 1; lb = g - NBUK1; }
    else                        { rel = 2; lb = g - NBUK1 - NBUK2; }
    int shift   = rel == 1 ? 6 : 9;
    int bpb     = rel == 1 ? 64 : 512;
    int binBase = rel == 0 ? 0 : (rel == 1 ? NN : NN + NH);
    int nbins   = rel == 1 ? NH : NN;
    int keyBase = lb << shift;
    int cntT = totals[g];
    int e0   = bucketBase[g];
    const u32* pb = pairs + (size_t)g * CAP;

    __shared__ int h[512];
    __shared__ int cur[512];
    __shared__ int wsum[4];
    int tid = threadIdx.x;
    for (int i = tid; i < 512; i += 256) h[i] = 0;
    __syncthreads();
    for (int i = tid; i < cntT; i += 256)
        atomicAdd(&h[pb[i] >> 17], 1);
    __syncthreads();

    // block exclusive scan over h[0..512) -> cur
    int j0 = 2 * tid;
    int v0 = h[j0], v1 = h[j0 + 1];
    int s = v0 + v1;
    int lane = tid & 63, wid = tid >> 6;
    int sc = s;
#pragma unroll
    for (int o = 1; o < 64; o <<= 1) {
        int t = __shfl_up(sc, o, 64);
        if (lane >= o) sc += t;
    }
    if (lane == 63) wsum[wid] = sc;
    __syncthreads();
    int woff = 0;
    for (int w = 0; w < wid; ++w) woff += wsum[w];
    int excl = woff + sc - s;
    cur[j0] = excl;
    cur[j0 + 1] = excl + v0;
    __syncthreads();

    // rowptr + degree outputs for this bucket's bins
    for (int i = tid; i < bpb; i += 256) {
        int bin = keyBase + i;
        if (bin < nbins) {
            rowptr[binBase + bin] = e0 + cur[i];
            int cnt = h[i];
            if (rel == 0)      dinv[bin] = rsqrtf((float)cnt + 1.0f);
            else if (rel == 1) Binv[bin] = cnt > 0 ? 1.0f / (float)cnt : 0.0f;
            else               Dinv[bin] = cnt > 0 ? 1.0f / (float)cnt : 0.0f;
        }
    }
    __syncthreads();

    // scatter values into final CSR positions
    for (int i = tid; i < cntT; i += 256) {
        u32 p = pb[i];
        int pos = atomicAdd(&cur[p >> 17], 1);
        colAll[e0 + pos] = (int)(p & 0x1FFFFu);
    }
}

// ---- GEMM: Y[r][c] = (sum_k X[r][k] * W[k][c]) * scale?[r] -> bf16 --------

template <int K, bool SCALE, bool INBF>
__global__ __launch_bounds__(256) void k_gemm(const void* __restrict__ Xv,
                                              const float* __restrict__ W,
                                              const float* __restrict__ scale,
                                              u16* __restrict__ Y, int n) {
    __shared__ float4 Wl[D * K / 4];
    for (int i = threadIdx.x; i < D * K / 4; i += 256)
        Wl[i] = reinterpret_cast<const float4*>(W)[i];
    __syncthreads();

    int r = blockIdx.x * 256 + threadIdx.x;
    if (r >= n) return;

    float xr[D];
    if (INBF) {
        const uint4* x4 = reinterpret_cast<const uint4*>((const u16*)Xv + (size_t)r * D);
#pragma unroll
        for (int i = 0; i < D / 8; ++i) {
            uint4 v = x4[i];
            xr[8 * i + 0] = __builtin_bit_cast(float, v.x << 16);
            xr[8 * i + 1] = __builtin_bit_cast(float, v.x & 0xFFFF0000u);
            xr[8 * i + 2] = __builtin_bit_cast(float, v.y << 16);
            xr[8 * i + 3] = __builtin_bit_cast(float, v.y & 0xFFFF0000u);
            xr[8 * i + 4] = __builtin_bit_cast(float, v.z << 16);
            xr[8 * i + 5] = __builtin_bit_cast(float, v.z & 0xFFFF0000u);
            xr[8 * i + 6] = __builtin_bit_cast(float, v.w << 16);
            xr[8 * i + 7] = __builtin_bit_cast(float, v.w & 0xFFFF0000u);
        }
    } else {
        const float4* x4 = reinterpret_cast<const float4*>((const float*)Xv + (size_t)r * D);
#pragma unroll
        for (int i = 0; i < D / 4; ++i) {
            float4 v = x4[i];
            xr[4 * i + 0] = v.x; xr[4 * i + 1] = v.y;
            xr[4 * i + 2] = v.z; xr[4 * i + 3] = v.w;
        }
    }

    float acc[K];
#pragma unroll
    for (int c = 0; c < K; ++c) acc[c] = 0.0f;

#pragma unroll
    for (int k = 0; k < D; ++k) {
        float xv = xr[k];
#pragma unroll
        for (int c4 = 0; c4 < K / 4; ++c4) {
            float4 w = Wl[k * (K / 4) + c4];
            acc[4 * c4 + 0] = fmaf(xv, w.x, acc[4 * c4 + 0]);
            acc[4 * c4 + 1] = fmaf(xv, w.y, acc[4 * c4 + 1]);
            acc[4 * c4 + 2] = fmaf(xv, w.z, acc[4 * c4 + 2]);
            acc[4 * c4 + 3] = fmaf(xv, w.w, acc[4 * c4 + 3]);
        }
    }

    float s = SCALE ? scale[r] : 1.0f;
    uint4* y4 = reinterpret_cast<uint4*>(Y + (size_t)r * K);
#pragma unroll
    for (int j = 0; j < K / 8; ++j) {
        uint4 o;
        o.x = pack2(acc[8 * j + 0] * s, acc[8 * j + 1] * s);
        o.y = pack2(acc[8 * j + 2] * s, acc[8 * j + 3] * s);
        o.z = pack2(acc[8 * j + 4] * s, acc[8 * j + 5] * s);
        o.w = pack2(acc[8 * j + 6] * s, acc[8 * j + 7] * s);
        y4[j] = o;
    }
}

// ---- fused: xa = branch_attention(x1, xh, aw); Y = (xa @ W)*dinv -> bf16 --

__global__ __launch_bounds__(256) void k_gemm_attn(const u16* __restrict__ X1,
                                                   const u16* __restrict__ XH,
                                                   const float* __restrict__ aw,
                                                   const float* __restrict__ W,
                                                   const float* __restrict__ scale,
                                                   u16* __restrict__ Y, int n) {
    __shared__ float4 Wl[D * C / 4];
    __shared__ float awl[2 * D];
    for (int i = threadIdx.x; i < D * C / 4; i += 256)
        Wl[i] = reinterpret_cast<const float4*>(W)[i];
    for (int i = threadIdx.x; i < 2 * D; i += 256) awl[i] = aw[i];
    __syncthreads();

    int r = blockIdx.x * 256 + threadIdx.x;
    if (r >= n) return;

    float a[D], h[D];
    {
        const uint4* x4 = reinterpret_cast<const uint4*>(X1 + (size_t)r * D);
        const uint4* h4 = reinterpret_cast<const uint4*>(XH + (size_t)r * D);
#pragma unroll
        for (int i = 0; i < D / 8; ++i) {
            uint4 v = x4[i];
            a[8 * i + 0] = __builtin_bit_cast(float, v.x << 16);
            a[8 * i + 1] = __builtin_bit_cast(float, v.x & 0xFFFF0000u);
            a[8 * i + 2] = __builtin_bit_cast(float, v.y << 16);
            a[8 * i + 3] = __builtin_bit_cast(float, v.y & 0xFFFF0000u);
            a[8 * i + 4] = __builtin_bit_cast(float, v.z << 16);
            a[8 * i + 5] = __builtin_bit_cast(float, v.z & 0xFFFF0000u);
            a[8 * i + 6] = __builtin_bit_cast(float, v.w << 16);
            a[8 * i + 7] = __builtin_bit_cast(float, v.w & 0xFFFF0000u);
            uint4 u = h4[i];
            h[8 * i + 0] = __builtin_bit_cast(float, u.x << 16);
            h[8 * i + 1] = __builtin_bit_cast(float, u.x & 0xFFFF0000u);
            h[8 * i + 2] = __builtin_bit_cast(float, u.y << 16);
            h[8 * i + 3] = __builtin_bit_cast(float, u.y & 0xFFFF0000u);
            h[8 * i + 4] = __builtin_bit_cast(float, u.z << 16);
            h[8 * i + 5] = __builtin_bit_cast(float, u.z & 0xFFFF0000u);
            h[8 * i + 6] = __builtin_bit_cast(float, u.w << 16);
            h[8 * i + 7] = __builtin_bit_cast(float, u.w & 0xFFFF0000u);
        }
    }

    float s0 = 0.0f, s1 = 0.0f;
#pragma unroll
    for (int k = 0; k < D; ++k) {
        s0 = fmaf(a[k], awl[2 * k + 0], s0);
        s1 = fmaf(h[k], awl[2 * k + 1], s1);
    }
    float m = fmaxf(s0, s1);
    float e0 = expf(s0 - m), e1 = expf(s1 - m);
    float inv = 1.0f / (e0 + e1);
    float a0 = e0 * inv, a1 = e1 * inv;
#pragma unroll
    for (int k = 0; k < D; ++k) a[k] = a0 * a[k] + a1 * h[k];

    float acc[C];
#pragma unroll
    for (int c = 0; c < C; ++c) acc[c] = 0.0f;
#pragma unroll
    for (int k = 0; k < D; ++k) {
        float xv = a[k];
#pragma unroll
        for (int c4 = 0; c4 < C / 4; ++c4) {
            float4 w = Wl[k * (C / 4) + c4];
            acc[4 * c4 + 0] = fmaf(xv, w.x, acc[4 * c4 + 0]);
            acc[4 * c4 + 1] = fmaf(xv, w.y, acc[4 * c4 + 1]);
            acc[4 * c4 + 2] = fmaf(xv, w.z, acc[4 * c4 + 2]);
            acc[4 * c4 + 3] = fmaf(xv, w.w, acc[4 * c4 + 3]);
        }
    }
    float s = scale[r];
    uint4* y4 = reinterpret_cast<uint4*>(Y + (size_t)r * C);
#pragma unroll
    for (int j = 0; j < C / 8; ++j) {
        uint4 o;
        o.x = pack2(acc[8 * j + 0] * s, acc[8 * j + 1] * s);
        o.y = pack2(acc[8 * j + 2] * s, acc[8 * j + 3] * s);
        o.z = pack2(acc[8 * j + 4] * s, acc[8 * j + 5] * s);
        o.w = pack2(acc[8 * j + 6] * s, acc[8 * j + 7] * s);
        y4[j] = o;
    }
}

// ---- GCN gather+finalize (bf16 sources, f32 acc, 8x unrolled) -------------

template <int K, bool RELU, bool OUTBF>
__global__ void k_gcn_gather(const int* __restrict__ rp, const int* __restrict__ col,
                             const u16* __restrict__ G, const float* __restrict__ dinv,
                             const float* __restrict__ b, void* __restrict__ out, int n) {
    int t = blockIdx.x * blockDim.x + threadIdx.x;
    int i = t >> 6, f = t & 63;
    if (i >= n) return;
    int e0 = __builtin_amdgcn_readfirstlane(rp[i]);
    int e1 = __builtin_amdgcn_readfirstlane(rp[i + 1]);
    float a0 = bf2f(G[(size_t)i * K + f]);  // self loop
    float a1 = 0.f, a2 = 0.f, a3 = 0.f, a4 = 0.f, a5 = 0.f, a6 = 0.f, a7 = 0.f;
    int e = e0;
    for (; e + 8 <= e1; e += 8) {
        int s0 = col[e], s1 = col[e + 1], s2 = col[e + 2], s3 = col[e + 3];
        int s4 = col[e + 4], s5 = col[e + 5], s6 = col[e + 6], s7 = col[e + 7];
        a0 += bf2f(G[(size_t)s0 * K + f]);
        a1 += bf2f(G[(size_t)s1 * K + f]);
        a2 += bf2f(G[(size_t)s2 * K + f]);
        a3 += bf2f(G[(size_t)s3 * K + f]);
        a4 += bf2f(G[(size_t)s4 * K + f]);
        a5 += bf2f(G[(size_t)s5 * K + f]);
        a6 += bf2f(G[(size_t)s6 * K + f]);
        a7 += bf2f(G[(size_t)s7 * K + f]);
    }
    if (e + 4 <= e1) {
        int s0 = col[e], s1 = col[e + 1], s2 = col[e + 2], s3 = col[e + 3];
        a0 += bf2f(G[(size_t)s0 * K + f]);
        a1 += bf2f(G[(size_t)s1 * K + f]);
        a2 += bf2f(G[(size_t)s2 * K + f]);
        a3 += bf2f(G[(size_t)s3 * K + f]);
        e += 4;
    }
    for (; e < e1; ++e) a0 += bf2f(G[(size_t)col[e] * K + f]);
    if ((K == 64) || (f < K)) {
        float v = dinv[i] * (((a0 + a1) + (a2 + a3)) + ((a4 + a5) + (a6 + a7))) + b[f];
        if (RELU) v = fmaxf(v, 0.0f);
        if (OUTBF) ((u16*)out)[(size_t)i * K + f] = f2bf(v);
        else       ((float*)out)[(size_t)i * K + f] = v;
    }
}

// ---- hyper phase A: M[h] = bf16(Binv[h] * sum_e G[col[e]]) ----------------

template <int K>
__global__ void k_hypA(const int* __restrict__ rp, const int* __restrict__ col,
                       const u16* __restrict__ G, const float* __restrict__ Binv,
                       u16* __restrict__ M, int nh) {
    int t = blockIdx.x * blockDim.x + threadIdx.x;
    int i = t >> 6, f = t & 63;
    if (i >= nh) return;
    int e0 = __builtin_amdgcn_readfirstlane(rp[i]);
    int e1 = __builtin_amdgcn_readfirstlane(rp[i + 1]);
    float a0 = 0.f, a1 = 0.f, a2 = 0.f, a3 = 0.f, a4 = 0.f, a5 = 0.f, a6 = 0.f, a7 = 0.f;
    int e = e0;
    for (; e + 8 <= e1; e += 8) {
        int s0 = col[e], s1 = col[e + 1], s2 = col[e + 2], s3 = col[e + 3];
        int s4 = col[e + 4], s5 = col[e + 5], s6 = col[e + 6], s7 = col[e + 7];
        a0 += bf2f(G[(size_t)s0 * K + f]);
        a1 += bf2f(G[(size_t)s1 * K + f]);
        a2 += bf2f(G[(size_t)s2 * K + f]);
        a3 += bf2f(G[(size_t)s3 * K + f]);
        a4 += bf2f(G[(size_t)s4 * K + f]);
        a5 += bf2f(G[(size_t)s5 * K + f]);
        a6 += bf2f(G[(size_t)s6 * K + f]);
        a7 += bf2f(G[(size_t)s7 * K + f]);
    }
    if (e + 4 <= e1) {
        int s0 = col[e], s1 = col[e + 1], s2 = col[e + 2], s3 = col[e + 3];
        a0 += bf2f(G[(size_t)s0 * K + f]);
        a1 += bf2f(G[(size_t)s1 * K + f]);
        a2 += bf2f(G[(size_t)s2 * K + f]);
        a3 += bf2f(G[(size_t)s3 * K + f]);
        e += 4;
    }
    for (; e < e1; ++e) a0 += bf2f(G[(size_t)col[e] * K + f]);
    if ((K == 64) || (f < K))
        M[(size_t)i * K + f] =
            f2bf((((a0 + a1) + (a2 + a3)) + ((a4 + a5) + (a6 + a7))) * Binv[i]);
}

// ---- hyper phase B: out[i] = relu?(Dinv[i] * sum_e M[col[e]] + b) ---------

template <int K, bool RELU, bool OUTBF>
__global__ void k_hypB(const int* __restrict__ rp, const int* __restrict__ col,
                       const u16* __restrict__ M, const float* __restrict__ Dinv,
                       const float* __restrict__ b, void* __restrict__ out, int n) {
    int t = blockIdx.x * blockDim.x + threadIdx.x;
    int i = t >> 6, f = t & 63;
    if (i >= n) return;
    int e0 = __builtin_amdgcn_readfirstlane(rp[i]);
    int e1 = __builtin_amdgcn_readfirstlane(rp[i + 1]);
    float a0 = 0.f, a1 = 0.f, a2 = 0.f, a3 = 0.f, a4 = 0.f, a5 = 0.f, a6 = 0.f, a7 = 0.f;
    int e = e0;
    for (; e + 8 <= e1; e += 8) {
        int s0 = col[e], s1 = col[e + 1], s2 = col[e + 2], s3 = col[e + 3];
        int s4 = col[e + 4], s5 = col[e + 5], s6 = col[e + 6], s7 = col[e + 7];
        a0 += bf2f(M[(size_t)s0 * K + f]);
        a1 += bf2f(M[(size_t)s1 * K + f]);
        a2 += bf2f(M[(size_t)s2 * K + f]);
        a3 += bf2f(M[(size_t)s3 * K + f]);
        a4 += bf2f(M[(size_t)s4 * K + f]);
        a5 += bf2f(M[(size_t)s5 * K + f]);
        a6 += bf2f(M[(size_t)s6 * K + f]);
        a7 += bf2f(M[(size_t)s7 * K + f]);
    }
    if (e + 4 <= e1) {
        int s0 = col[e], s1 = col[e + 1], s2 = col[e + 2], s3 = col[e + 3];
        a0 += bf2f(M[(size_t)s0 * K + f]);
        a1 += bf2f(M[(size_t)s1 * K + f]);
        a2 += bf2f(M[(size_t)s2 * K + f]);
        a3 += bf2f(M[(size_t)s3 * K + f]);
        e += 4;
    }
    for (; e < e1; ++e) a0 += bf2f(M[(size_t)col[e] * K + f]);
    if ((K == 64) || (f < K)) {
        float v = (((a0 + a1) + (a2 + a3)) + ((a4 + a5) + (a6 + a7))) * Dinv[i] + b[f];
        if (RELU) v = fmaxf(v, 0.0f);
        if (OUTBF) ((u16*)out)[(size_t)i * K + f] = f2bf(v);
        else       ((float*)out)[(size_t)i * K + f] = v;
    }
}

// ---- branch attention (K = 40) + log_softmax ------------------------------

__global__ void k_attn_lsm(const float* __restrict__ X, const float* __restrict__ Xh,
                           const float* __restrict__ w, float* __restrict__ out, int n) {
    int t = blockIdx.x * blockDim.x + threadIdx.x;
    int node = t >> 6, lane = t & 63;
    if (node >= n) return;
    bool act = lane < C;
    int idx = node * C + lane;
    float xv = act ? X[idx] : 0.0f;
    float hv = act ? Xh[idx] : 0.0f;
    float p0 = act ? xv * w[2 * lane + 0] : 0.0f;
    float p1 = act ? hv * w[2 * lane + 1] : 0.0f;
#pragma unroll
    for (int o = 32; o; o >>= 1) {
        p0 += __shfl_xor(p0, o, 64);
        p1 += __shfl_xor(p1, o, 64);
    }
    float m = fmaxf(p0, p1);
    float e0 = expf(p0 - m), e1 = expf(p1 - m);
    float inv = 1.0f / (e0 + e1);
    float v = (e0 * xv + e1 * hv) * inv;

    float mv = act ? v : -1e30f;
#pragma unroll
    for (int o = 32; o; o >>= 1) mv = fmaxf(mv, __shfl_xor(mv, o, 64));
    float ex = act ? expf(v - mv) : 0.0f;
    float s = ex;
#pragma unroll
    for (int o = 32; o; o >>= 1) s += __shfl_xor(s, o, 64);
    float lse = mv + logf(s);
    if (act) out[idx] = v - lse;
}

}  // namespace

extern "C" void kernel_launch(void* const* d_in, const int* in_sizes, int n_in,
                              void* d_out, int out_size, void* d_ws, size_t ws_size,
                              hipStream_t stream) {
    const float* x     = (const float*)d_in[0];
    const int*   ei    = (const int*)d_in[1];
    const int*   esrc  = ei;
    const int*   edst  = ei + NE;
    const int*   hnode = (const int*)d_in[2];
    const int*   hid   = (const int*)d_in[3];
    const float* W1g = (const float*)d_in[4];
    const float* b1g = (const float*)d_in[5];
    const float* W1h = (const float*)d_in[6];
    const float* b1h = (const float*)d_in[7];
    const float* aw1 = (const float*)d_in[8];
    const float* W2g = (const float*)d_in[9];
    const float* b2g = (const float*)d_in[10];
    const float* W2h = (const float*)d_in[11];
    const float* b2h = (const float*)d_in[12];
    const float* aw2 = (const float*)d_in[13];
    float* out = (float*)d_out;

    char* ws = (char*)d_ws;
    size_t off = 0;
    auto alloc = [&](size_t bytes) -> void* {
        void* p = (void*)(ws + off);
        off = (off + bytes + 255) & ~(size_t)255;
        return p;
    };
    float* dinv   = (float*)alloc((size_t)NN * 4);
    float* Binv   = (float*)alloc((size_t)NH * 4);
    float* Dinv   = (float*)alloc((size_t)NN * 4);
    int*   rpAll  = (int*)alloc((size_t)(NT + 1) * 4);
    int*   colAll = (int*)alloc((size_t)(NE + 2 * (size_t)NI) * 4);  // 14.4 MB
    int*   gcur   = (int*)alloc((size_t)NBUKT * 4);
    int*   bukB   = (int*)alloc((size_t)(NBUKT + 1) * 4);
    // union region: pairs slack (22.5 MB, build-time) / A16,X1,XH16 (38.4 MB)
    char*  U      = (char*)alloc((size_t)3 * NN * D * 2);
    u32*   pairs  = (u32*)U;
    u16*   A16    = (u16*)U;
    u16*   X1     = (u16*)(U + (size_t)NN * D * 2);
    u16*   XH16   = (u16*)(U + (size_t)2 * NN * D * 2);
    u16*   M16    = (u16*)alloc((size_t)NH * D * 2);
    float* X2f    = (float*)alloc((size_t)NN * C * 4);
    float* XH2f   = (float*)alloc((size_t)NN * C * 4);

    const int B = 256;
    int gNN  = (NN + 255) / 256;
    int gN64 = NN * 64 / 256;          // 25000 blocks, 1 wave per node
    int gH64 = NH * 64 / 256;          // 2500

    // ---- build CSR + degrees (hist+reserve+scatter, fine sort, fused degs) ----
    hipMemsetAsync(gcur, 0, (size_t)NBUKT * 4, stream);
    k_build<<<3 * NBLK, B, 0, stream>>>(esrc, edst, hid, hnode, gcur, pairs);
    k_s2<<<1, 64, 0, stream>>>(gcur, bukB, rpAll);
    k_p3<<<NBUKT, B, 0, stream>>>(pairs, gcur, bukB, rpAll, colAll, dinv, Binv, Dinv);

    // ---- layer 1 GCN: x1 = relu(dinv*(self + gather) + b1g) ----
    k_gemm<64, true, false><<<gNN, B, 0, stream>>>(x, W1g, dinv, A16, NN);
    k_gcn_gather<64, true, true><<<gN64, B, 0, stream>>>(rpAll, colAll, A16, dinv, b1g, X1, NN);

    // ---- layer 1 hypergraph on x1 ----
    k_gemm<64, false, true><<<gNN, B, 0, stream>>>(X1, W1h, nullptr, A16, NN);
    k_hypA<64><<<gH64, B, 0, stream>>>(rpAll + OFF_H, colAll, A16, Binv, M16, NH);
    k_hypB<64, true, true><<<gN64, B, 0, stream>>>(rpAll + OFF_N, colAll, M16, Dinv, b1h, XH16, NN);

    // ---- attn1 fused into layer-2 GCN GEMM: G2 = (attn(x1,xh)@W2g)*dinv ----
    k_gemm_attn<<<gNN, B, 0, stream>>>(X1, XH16, aw1, W2g, dinv, A16, NN);
    k_gcn_gather<40, false, false><<<gN64, B, 0, stream>>>(rpAll, colAll, A16, dinv, b2g, X2f, NN);

    // ---- layer 2 hypergraph on x_hyper ----
    k_gemm<40, false, true><<<gNN, B, 0, stream>>>(XH16, W2h, nullptr, X1, NN);  // X1 = G4
    k_hypA<40><<<gH64, B, 0, stream>>>(rpAll + OFF_H, colAll, X1, Binv, M16, NH);
    k_hypB<40, false, false><<<gN64, B, 0, stream>>>(rpAll + OFF_N, colAll, M16, Dinv, b2h, XH2f, NN);

    // ---- attention 2 + log_softmax -> out ----
    k_attn_lsm<<<gN64, B, 0, stream>>>(X2f, XH2f, aw2, out, NN);
}

// Round 6
// 416.289 us; speedup vs baseline: 4.5108x; 1.0404x over previous
//
#include <hip/hip_runtime.h>
#include <math.h>

namespace {

constexpr int NN = 100000;   // nodes
constexpr int NE = 1200000;  // edges
constexpr int NH = 10000;    // hyperedges
constexpr int NI = 1200000;  // incidences
constexpr int D  = 64;       // hidden dim
constexpr int C  = 40;       // classes

constexpr int OFF_H = NN;         // hyperedge rowptr offset
constexpr int OFF_N = NN + NH;    // node-incidence rowptr offset
constexpr int NT    = NN + NH + NN;

// bucket sort: rel0 = edges by dst, rel1 = incid by hyperedge, rel2 = incid by node
constexpr int NBLK   = 150;                 // partition blocks per relation
constexpr int CHUNK  = 8000;                // NI / NBLK (exact)
constexpr int NBUK1  = 196;                 // ceil(100000 / 512)
constexpr int NBUK2  = 157;                 // ceil(10000 / 64)
constexpr int NBUK3  = 196;
constexpr int NBUKT  = NBUK1 + NBUK2 + NBUK3;  // 549
constexpr int CAP    = 10240;               // slack region per bucket (max total ~8.1K)

using u16 = unsigned short;
using u32 = unsigned int;

__device__ __forceinline__ float bf2f(u16 u) {
    u32 v = (u32)u << 16;
    return __builtin_bit_cast(float, v);
}
__device__ __forceinline__ u16 f2bf(float f) {
    u32 u = __builtin_bit_cast(u32, f);
    return (u16)((u + 0x7FFFu + ((u >> 16) & 1u)) >> 16);
}
__device__ __forceinline__ u32 pack2(float a, float b) {
    return (u32)f2bf(a) | ((u32)f2bf(b) << 16);
}

// ---- BUILD: LDS multisplit -> coalesced per-bucket-run writes -------------

__global__ __launch_bounds__(256) void k_build(const int* __restrict__ esrc,
                                               const int* __restrict__ edst,
                                               const int* __restrict__ hid,
                                               const int* __restrict__ hnode,
                                               int* __restrict__ gcur,
                                               u32* __restrict__ pairs) {
    int rel = blockIdx.x / NBLK, blk = blockIdx.x % NBLK;
    const int *keys, *vals;
    if (rel == 0)      { keys = edst;  vals = esrc;  }
    else if (rel == 1) { keys = hid;   vals = hnode; }
    else               { keys = hnode; vals = hid;   }
    int bukBase = rel == 0 ? 0 : (rel == 1 ? NBUK1 : NBUK1 + NBUK2);
    int nbuk    = rel == 1 ? NBUK2 : NBUK1;
    int shift   = rel == 1 ? 6 : 9;
    int mask    = (1 << shift) - 1;

    __shared__ int h[NBUK1];          // hist, then reused as cursor
    __shared__ int lofs[NBUK1 + 1];   // exclusive scan of hist
    __shared__ int gbase[NBUK1];      // reserved global offset per bucket
    __shared__ u32 stage[CHUNK];      // 32 KB bucket-sorted staging

    int tid = threadIdx.x;
    for (int i = tid; i < nbuk; i += 256) h[i] = 0;
    __syncthreads();

    int start = blk * CHUNK;
    const int4* k4 = reinterpret_cast<const int4*>(keys + start);
    const int4* v4 = reinterpret_cast<const int4*>(vals + start);

    // pass 1: histogram
    for (int i = tid; i < CHUNK / 4; i += 256) {
        int4 kk = k4[i];
        atomicAdd(&h[kk.x >> shift], 1);
        atomicAdd(&h[kk.y >> shift], 1);
        atomicAdd(&h[kk.z >> shift], 1);
        atomicAdd(&h[kk.w >> shift], 1);
    }
    __syncthreads();

    // scan h -> lofs (wave 0 only)
    if (tid < 64) {
        int acc = 0;
        for (int base = 0; base < nbuk; base += 64) {
            int idx = base + tid;
            int v = idx < nbuk ? h[idx] : 0;
            int sc = v;
#pragma unroll
            for (int o = 1; o < 64; o <<= 1) {
                int t = __shfl_up(sc, o, 64);
                if (tid >= o) sc += t;
            }
            if (idx < nbuk) lofs[idx] = acc + sc - v;
            acc += __shfl(sc, 63, 64);
        }
        if (tid == 0) lofs[nbuk] = acc;  // == CHUNK
    }
    __syncthreads();

    // reserve global ranges, then convert h to stage cursor
    for (int i = tid; i < nbuk; i += 256) gbase[i] = atomicAdd(&gcur[bukBase + i], h[i]);
    __syncthreads();
    for (int i = tid; i < nbuk; i += 256) h[i] = lofs[i];
    __syncthreads();

    // pass 2: stage bucket-sorted into LDS
    for (int i = tid; i < CHUNK / 4; i += 256) {
        int4 kk = k4[i];
        int4 vv = v4[i];
        int p0 = atomicAdd(&h[kk.x >> shift], 1);
        stage[p0] = ((u32)(kk.x & mask) << 17) | (u32)vv.x;
        int p1 = atomicAdd(&h[kk.y >> shift], 1);
        stage[p1] = ((u32)(kk.y & mask) << 17) | (u32)vv.y;
        int p2 = atomicAdd(&h[kk.z >> shift], 1);
        stage[p2] = ((u32)(kk.z & mask) << 17) | (u32)vv.z;
        int p3 = atomicAdd(&h[kk.w >> shift], 1);
        stage[p3] = ((u32)(kk.w & mask) << 17) | (u32)vv.w;
    }
    __syncthreads();

    // write out: each wave streams whole bucket runs (coalesced)
    int wid = tid >> 6, lane = tid & 63;
    for (int buk = wid; buk < nbuk; buk += 4) {
        int s0 = lofs[buk], s1 = lofs[buk + 1];
        int gb = gbase[buk];
        u32* dst = pairs + (size_t)(bukBase + buk) * CAP + gb;
        int cnt = s1 - s0;
        if (gb + cnt > CAP) cnt = CAP - gb;  // defensive (never hit by construction)
        for (int j = lane; j < cnt; j += 64) dst[j] = stage[s0 + j];
    }
}

// ---- P3: per-bucket fine counting sort -> rowptr + colAll + degrees -------

__global__ __launch_bounds__(256) void k_p3(const u32* __restrict__ pairs,
                                            const int* __restrict__ totals,
                                            int* __restrict__ rowptr,
                                            int* __restrict__ colAll,
                                            float* __restrict__ dinv,
                                            float* __restrict__ Binv,
                                            float* __restrict__ Dinv) {
    int g = blockIdx.x;
    int rel, lb;
    if (g < NBUK1)              { rel = 0; lb = g; }
    else if (g < NBUK1 + NBUK2) { rel = 1; lb = g - NBUK1; }
    else                        { rel = 2; lb = g - NBUK1 - NBUK2; }
    int shift   = rel == 1 ? 6 : 9;
    int bpb     = rel == 1 ? 64 : 512;
    int binBase = rel == 0 ? 0 : (rel == 1 ? NN : NN + NH);
    int nbins   = rel == 1 ? NH : NN;
    int keyBase = lb << shift;
    int tid = threadIdx.x;
    int lane = tid & 63, wid = tid >> 6;

    // e0 = sum(totals[0..g)) via block reduction
    __shared__ int wred[4];
    int partial = 0;
    for (int j = tid; j < g; j += 256) partial += totals[j];
#pragma unroll
    for (int o = 32; o; o >>= 1) partial += __shfl_xor(partial, o, 64);
    if (lane == 0) wred[wid] = partial;
    __syncthreads();
    int e0 = wred[0] + wred[1] + wred[2] + wred[3];
    int cntT = totals[g];
    if (g == NBUKT - 1 && tid == 0) rowptr[NT] = e0 + cntT;

    const u32* pb = pairs + (size_t)g * CAP;

    __shared__ int h[512];
    __shared__ int cur[512];
    __shared__ int wsum[4];
    for (int i = tid; i < 512; i += 256) h[i] = 0;
    __syncthreads();
    for (int i = tid; i < cntT; i += 256)
        atomicAdd(&h[pb[i] >> 17], 1);
    __syncthreads();

    // block exclusive scan over h[0..512) -> cur
    int j0 = 2 * tid;
    int v0 = h[j0], v1 = h[j0 + 1];
    int s = v0 + v1;
    int sc = s;
#pragma unroll
    for (int o = 1; o < 64; o <<= 1) {
        int t = __shfl_up(sc, o, 64);
        if (lane >= o) sc += t;
    }
    if (lane == 63) wsum[wid] = sc;
    __syncthreads();
    int woff = 0;
    for (int w = 0; w < wid; ++w) woff += wsum[w];
    int excl = woff + sc - s;
    cur[j0] = excl;
    cur[j0 + 1] = excl + v0;
    __syncthreads();

    // rowptr + degree outputs for this bucket's bins
    for (int i = tid; i < bpb; i += 256) {
        int bin = keyBase + i;
        if (bin < nbins) {
            rowptr[binBase + bin] = e0 + cur[i];
            int cnt = h[i];
            if (rel == 0)      dinv[bin] = rsqrtf((float)cnt + 1.0f);
            else if (rel == 1) Binv[bin] = cnt > 0 ? 1.0f / (float)cnt : 0.0f;
            else               Dinv[bin] = cnt > 0 ? 1.0f / (float)cnt : 0.0f;
        }
    }
    __syncthreads();

    // scatter values into final CSR positions
    for (int i = tid; i < cntT; i += 256) {
        u32 p = pb[i];
        int pos = atomicAdd(&cur[p >> 17], 1);
        colAll[e0 + pos] = (int)(p & 0x1FFFFu);
    }
}

// ---- GEMM: Y[r][c] = (sum_k X[r][k] * W[k][c]) * scale?[r] -> bf16 --------

template <int K, bool SCALE, bool INBF>
__global__ __launch_bounds__(256) void k_gemm(const void* __restrict__ Xv,
                                              const float* __restrict__ W,
                                              const float* __restrict__ scale,
                                              u16* __restrict__ Y, int n) {
    __shared__ float4 Wl[D * K / 4];
    for (int i = threadIdx.x; i < D * K / 4; i += 256)
        Wl[i] = reinterpret_cast<const float4*>(W)[i];
    __syncthreads();

    int r = blockIdx.x * 256 + threadIdx.x;
    if (r >= n) return;

    float xr[D];
    if (INBF) {
        const uint4* x4 = reinterpret_cast<const uint4*>((const u16*)Xv + (size_t)r * D);
#pragma unroll
        for (int i = 0; i < D / 8; ++i) {
            uint4 v = x4[i];
            xr[8 * i + 0] = __builtin_bit_cast(float, v.x << 16);
            xr[8 * i + 1] = __builtin_bit_cast(float, v.x & 0xFFFF0000u);
            xr[8 * i + 2] = __builtin_bit_cast(float, v.y << 16);
            xr[8 * i + 3] = __builtin_bit_cast(float, v.y & 0xFFFF0000u);
            xr[8 * i + 4] = __builtin_bit_cast(float, v.z << 16);
            xr[8 * i + 5] = __builtin_bit_cast(float, v.z & 0xFFFF0000u);
            xr[8 * i + 6] = __builtin_bit_cast(float, v.w << 16);
            xr[8 * i + 7] = __builtin_bit_cast(float, v.w & 0xFFFF0000u);
        }
    } else {
        const float4* x4 = reinterpret_cast<const float4*>((const float*)Xv + (size_t)r * D);
#pragma unroll
        for (int i = 0; i < D / 4; ++i) {
            float4 v = x4[i];
            xr[4 * i + 0] = v.x; xr[4 * i + 1] = v.y;
            xr[4 * i + 2] = v.z; xr[4 * i + 3] = v.w;
        }
    }

    float acc[K];
#pragma unroll
    for (int c = 0; c < K; ++c) acc[c] = 0.0f;

#pragma unroll
    for (int k = 0; k < D; ++k) {
        float xv = xr[k];
#pragma unroll
        for (int c4 = 0; c4 < K / 4; ++c4) {
            float4 w = Wl[k * (K / 4) + c4];
            acc[4 * c4 + 0] = fmaf(xv, w.x, acc[4 * c4 + 0]);
            acc[4 * c4 + 1] = fmaf(xv, w.y, acc[4 * c4 + 1]);
            acc[4 * c4 + 2] = fmaf(xv, w.z, acc[4 * c4 + 2]);
            acc[4 * c4 + 3] = fmaf(xv, w.w, acc[4 * c4 + 3]);
        }
    }

    float s = SCALE ? scale[r] : 1.0f;
    uint4* y4 = reinterpret_cast<uint4*>(Y + (size_t)r * K);
#pragma unroll
    for (int j = 0; j < K / 8; ++j) {
        uint4 o;
        o.x = pack2(acc[8 * j + 0] * s, acc[8 * j + 1] * s);
        o.y = pack2(acc[8 * j + 2] * s, acc[8 * j + 3] * s);
        o.z = pack2(acc[8 * j + 4] * s, acc[8 * j + 5] * s);
        o.w = pack2(acc[8 * j + 6] * s, acc[8 * j + 7] * s);
        y4[j] = o;
    }
}

// ---- fused: xa = branch_attention(x1, xh, aw); Y = (xa @ W)*dinv -> bf16 --

__global__ __launch_bounds__(256) void k_gemm_attn(const u16* __restrict__ X1,
                                                   const u16* __restrict__ XH,
                                                   const float* __restrict__ aw,
                                                   const float* __restrict__ W,
                                                   const float* __restrict__ scale,
                                                   u16* __restrict__ Y, int n) {
    __shared__ float4 Wl[D * C / 4];
    __shared__ float awl[2 * D];
    for (int i = threadIdx.x; i < D * C / 4; i += 256)
        Wl[i] = reinterpret_cast<const float4*>(W)[i];
    for (int i = threadIdx.x; i < 2 * D; i += 256) awl[i] = aw[i];
    __syncthreads();

    int r = blockIdx.x * 256 + threadIdx.x;
    if (r >= n) return;

    float a[D], h[D];
    {
        const uint4* x4 = reinterpret_cast<const uint4*>(X1 + (size_t)r * D);
        const uint4* h4 = reinterpret_cast<const uint4*>(XH + (size_t)r * D);
#pragma unroll
        for (int i = 0; i < D / 8; ++i) {
            uint4 v = x4[i];
            a[8 * i + 0] = __builtin_bit_cast(float, v.x << 16);
            a[8 * i + 1] = __builtin_bit_cast(float, v.x & 0xFFFF0000u);
            a[8 * i + 2] = __builtin_bit_cast(float, v.y << 16);
            a[8 * i + 3] = __builtin_bit_cast(float, v.y & 0xFFFF0000u);
            a[8 * i + 4] = __builtin_bit_cast(float, v.z << 16);
            a[8 * i + 5] = __builtin_bit_cast(float, v.z & 0xFFFF0000u);
            a[8 * i + 6] = __builtin_bit_cast(float, v.w << 16);
            a[8 * i + 7] = __builtin_bit_cast(float, v.w & 0xFFFF0000u);
            uint4 u = h4[i];
            h[8 * i + 0] = __builtin_bit_cast(float, u.x << 16);
            h[8 * i + 1] = __builtin_bit_cast(float, u.x & 0xFFFF0000u);
            h[8 * i + 2] = __builtin_bit_cast(float, u.y << 16);
            h[8 * i + 3] = __builtin_bit_cast(float, u.y & 0xFFFF0000u);
            h[8 * i + 4] = __builtin_bit_cast(float, u.z << 16);
            h[8 * i + 5] = __builtin_bit_cast(float, u.z & 0xFFFF0000u);
            h[8 * i + 6] = __builtin_bit_cast(float, u.w << 16);
            h[8 * i + 7] = __builtin_bit_cast(float, u.w & 0xFFFF0000u);
        }
    }

    float s0 = 0.0f, s1 = 0.0f;
#pragma unroll
    for (int k = 0; k < D; ++k) {
        s0 = fmaf(a[k], awl[2 * k + 0], s0);
        s1 = fmaf(h[k], awl[2 * k + 1], s1);
    }
    float m = fmaxf(s0, s1);
    float e0 = expf(s0 - m), e1 = expf(s1 - m);
    float inv = 1.0f / (e0 + e1);
    float a0 = e0 * inv, a1 = e1 * inv;
#pragma unroll
    for (int k = 0; k < D; ++k) a[k] = a0 * a[k] + a1 * h[k];

    float acc[C];
#pragma unroll
    for (int c = 0; c < C; ++c) acc[c] = 0.0f;
#pragma unroll
    for (int k = 0; k < D; ++k) {
        float xv = a[k];
#pragma unroll
        for (int c4 = 0; c4 < C / 4; ++c4) {
            float4 w = Wl[k * (C / 4) + c4];
            acc[4 * c4 + 0] = fmaf(xv, w.x, acc[4 * c4 + 0]);
            acc[4 * c4 + 1] = fmaf(xv, w.y, acc[4 * c4 + 1]);
            acc[4 * c4 + 2] = fmaf(xv, w.z, acc[4 * c4 + 2]);
            acc[4 * c4 + 3] = fmaf(xv, w.w, acc[4 * c4 + 3]);
        }
    }
    float s = scale[r];
    uint4* y4 = reinterpret_cast<uint4*>(Y + (size_t)r * C);
#pragma unroll
    for (int j = 0; j < C / 8; ++j) {
        uint4 o;
        o.x = pack2(acc[8 * j + 0] * s, acc[8 * j + 1] * s);
        o.y = pack2(acc[8 * j + 2] * s, acc[8 * j + 3] * s);
        o.z = pack2(acc[8 * j + 4] * s, acc[8 * j + 5] * s);
        o.w = pack2(acc[8 * j + 6] * s, acc[8 * j + 7] * s);
        y4[j] = o;
    }
}

// ---- GCN gather+finalize (bf16 sources, f32 acc, 8x unrolled) -------------

template <int K, bool RELU, bool OUTBF>
__global__ void k_gcn_gather(const int* __restrict__ rp, const int* __restrict__ col,
                             const u16* __restrict__ G, const float* __restrict__ dinv,
                             const float* __restrict__ b, void* __restrict__ out, int n) {
    int t = blockIdx.x * blockDim.x + threadIdx.x;
    int i = t >> 6, f = t & 63;
    if (i >= n) return;
    int e0 = __builtin_amdgcn_readfirstlane(rp[i]);
    int e1 = __builtin_amdgcn_readfirstlane(rp[i + 1]);
    float a0 = bf2f(G[(size_t)i * K + f]);  // self loop
    float a1 = 0.f, a2 = 0.f, a3 = 0.f, a4 = 0.f, a5 = 0.f, a6 = 0.f, a7 = 0.f;
    int e = e0;
    for (; e + 8 <= e1; e += 8) {
        int s0 = col[e], s1 = col[e + 1], s2 = col[e + 2], s3 = col[e + 3];
        int s4 = col[e + 4], s5 = col[e + 5], s6 = col[e + 6], s7 = col[e + 7];
        a0 += bf2f(G[(size_t)s0 * K + f]);
        a1 += bf2f(G[(size_t)s1 * K + f]);
        a2 += bf2f(G[(size_t)s2 * K + f]);
        a3 += bf2f(G[(size_t)s3 * K + f]);
        a4 += bf2f(G[(size_t)s4 * K + f]);
        a5 += bf2f(G[(size_t)s5 * K + f]);
        a6 += bf2f(G[(size_t)s6 * K + f]);
        a7 += bf2f(G[(size_t)s7 * K + f]);
    }
    if (e + 4 <= e1) {
        int s0 = col[e], s1 = col[e + 1], s2 = col[e + 2], s3 = col[e + 3];
        a0 += bf2f(G[(size_t)s0 * K + f]);
        a1 += bf2f(G[(size_t)s1 * K + f]);
        a2 += bf2f(G[(size_t)s2 * K + f]);
        a3 += bf2f(G[(size_t)s3 * K + f]);
        e += 4;
    }
    for (; e < e1; ++e) a0 += bf2f(G[(size_t)col[e] * K + f]);
    if ((K == 64) || (f < K)) {
        float v = dinv[i] * (((a0 + a1) + (a2 + a3)) + ((a4 + a5) + (a6 + a7))) + b[f];
        if (RELU) v = fmaxf(v, 0.0f);
        if (OUTBF) ((u16*)out)[(size_t)i * K + f] = f2bf(v);
        else       ((float*)out)[(size_t)i * K + f] = v;
    }
}

// ---- hyper phase A: M[h] = bf16(Binv[h] * sum_e G[col[e]]) ----------------

template <int K>
__global__ void k_hypA(const int* __restrict__ rp, const int* __restrict__ col,
                       const u16* __restrict__ G, const float* __restrict__ Binv,
                       u16* __restrict__ M, int nh) {
    int t = blockIdx.x * blockDim.x + threadIdx.x;
    int i = t >> 6, f = t & 63;
    if (i >= nh) return;
    int e0 = __builtin_amdgcn_readfirstlane(rp[i]);
    int e1 = __builtin_amdgcn_readfirstlane(rp[i + 1]);
    float a0 = 0.f, a1 = 0.f, a2 = 0.f, a3 = 0.f, a4 = 0.f, a5 = 0.f, a6 = 0.f, a7 = 0.f;
    int e = e0;
    for (; e + 8 <= e1; e += 8) {
        int s0 = col[e], s1 = col[e + 1], s2 = col[e + 2], s3 = col[e + 3];
        int s4 = col[e + 4], s5 = col[e + 5], s6 = col[e + 6], s7 = col[e + 7];
        a0 += bf2f(G[(size_t)s0 * K + f]);
        a1 += bf2f(G[(size_t)s1 * K + f]);
        a2 += bf2f(G[(size_t)s2 * K + f]);
        a3 += bf2f(G[(size_t)s3 * K + f]);
        a4 += bf2f(G[(size_t)s4 * K + f]);
        a5 += bf2f(G[(size_t)s5 * K + f]);
        a6 += bf2f(G[(size_t)s6 * K + f]);
        a7 += bf2f(G[(size_t)s7 * K + f]);
    }
    if (e + 4 <= e1) {
        int s0 = col[e], s1 = col[e + 1], s2 = col[e + 2], s3 = col[e + 3];
        a0 += bf2f(G[(size_t)s0 * K + f]);
        a1 += bf2f(G[(size_t)s1 * K + f]);
        a2 += bf2f(G[(size_t)s2 * K + f]);
        a3 += bf2f(G[(size_t)s3 * K + f]);
        e += 4;
    }
    for (; e < e1; ++e) a0 += bf2f(G[(size_t)col[e] * K + f]);
    if ((K == 64) || (f < K))
        M[(size_t)i * K + f] =
            f2bf((((a0 + a1) + (a2 + a3)) + ((a4 + a5) + (a6 + a7))) * Binv[i]);
}

// ---- hyper phase B: out[i] = relu?(Dinv[i] * sum_e M[col[e]] + b) ---------

template <int K, bool RELU, bool OUTBF>
__global__ void k_hypB(const int* __restrict__ rp, const int* __restrict__ col,
                       const u16* __restrict__ M, const float* __restrict__ Dinv,
                       const float* __restrict__ b, void* __restrict__ out, int n) {
    int t = blockIdx.x * blockDim.x + threadIdx.x;
    int i = t >> 6, f = t & 63;
    if (i >= n) return;
    int e0 = __builtin_amdgcn_readfirstlane(rp[i]);
    int e1 = __builtin_amdgcn_readfirstlane(rp[i + 1]);
    float a0 = 0.f, a1 = 0.f, a2 = 0.f, a3 = 0.f, a4 = 0.f, a5 = 0.f, a6 = 0.f, a7 = 0.f;
    int e = e0;
    for (; e + 8 <= e1; e += 8) {
        int s0 = col[e], s1 = col[e + 1], s2 = col[e + 2], s3 = col[e + 3];
        int s4 = col[e + 4], s5 = col[e + 5], s6 = col[e + 6], s7 = col[e + 7];
        a0 += bf2f(M[(size_t)s0 * K + f]);
        a1 += bf2f(M[(size_t)s1 * K + f]);
        a2 += bf2f(M[(size_t)s2 * K + f]);
        a3 += bf2f(M[(size_t)s3 * K + f]);
        a4 += bf2f(M[(size_t)s4 * K + f]);
        a5 += bf2f(M[(size_t)s5 * K + f]);
        a6 += bf2f(M[(size_t)s6 * K + f]);
        a7 += bf2f(M[(size_t)s7 * K + f]);
    }
    if (e + 4 <= e1) {
        int s0 = col[e], s1 = col[e + 1], s2 = col[e + 2], s3 = col[e + 3];
        a0 += bf2f(M[(size_t)s0 * K + f]);
        a1 += bf2f(M[(size_t)s1 * K + f]);
        a2 += bf2f(M[(size_t)s2 * K + f]);
        a3 += bf2f(M[(size_t)s3 * K + f]);
        e += 4;
    }
    for (; e < e1; ++e) a0 += bf2f(M[(size_t)col[e] * K + f]);
    if ((K == 64) || (f < K)) {
        float v = (((a0 + a1) + (a2 + a3)) + ((a4 + a5) + (a6 + a7))) * Dinv[i] + b[f];
        if (RELU) v = fmaxf(v, 0.0f);
        if (OUTBF) ((u16*)out)[(size_t)i * K + f] = f2bf(v);
        else       ((float*)out)[(size_t)i * K + f] = v;
    }
}

// ---- branch attention (K = 40, bf16 in) + log_softmax -> f32 --------------

__global__ void k_attn_lsm(const u16* __restrict__ X, const u16* __restrict__ Xh,
                           const float* __restrict__ w, float* __restrict__ out, int n) {
    int t = blockIdx.x * blockDim.x + threadIdx.x;
    int node = t >> 6, lane = t & 63;
    if (node >= n) return;
    bool act = lane < C;
    int idx = node * C + lane;
    float xv = act ? bf2f(X[idx]) : 0.0f;
    float hv = act ? bf2f(Xh[idx]) : 0.0f;
    float p0 = act ? xv * w[2 * lane + 0] : 0.0f;
    float p1 = act ? hv * w[2 * lane + 1] : 0.0f;
#pragma unroll
    for (int o = 32; o; o >>= 1) {
        p0 += __shfl_xor(p0, o, 64);
        p1 += __shfl_xor(p1, o, 64);
    }
    float m = fmaxf(p0, p1);
    float e0 = expf(p0 - m), e1 = expf(p1 - m);
    float inv = 1.0f / (e0 + e1);
    float v = (e0 * xv + e1 * hv) * inv;

    float mv = act ? v : -1e30f;
#pragma unroll
    for (int o = 32; o; o >>= 1) mv = fmaxf(mv, __shfl_xor(mv, o, 64));
    float ex = act ? expf(v - mv) : 0.0f;
    float s = ex;
#pragma unroll
    for (int o = 32; o; o >>= 1) s += __shfl_xor(s, o, 64);
    float lse = mv + logf(s);
    if (act) out[idx] = v - lse;
}

}  // namespace

extern "C" void kernel_launch(void* const* d_in, const int* in_sizes, int n_in,
                              void* d_out, int out_size, void* d_ws, size_t ws_size,
                              hipStream_t stream) {
    const float* x     = (const float*)d_in[0];
    const int*   ei    = (const int*)d_in[1];
    const int*   esrc  = ei;
    const int*   edst  = ei + NE;
    const int*   hnode = (const int*)d_in[2];
    const int*   hid   = (const int*)d_in[3];
    const float* W1g = (const float*)d_in[4];
    const float* b1g = (const float*)d_in[5];
    const float* W1h = (const float*)d_in[6];
    const float* b1h = (const float*)d_in[7];
    const float* aw1 = (const float*)d_in[8];
    const float* W2g = (const float*)d_in[9];
    const float* b2g = (const float*)d_in[10];
    const float* W2h = (const float*)d_in[11];
    const float* b2h = (const float*)d_in[12];
    const float* aw2 = (const float*)d_in[13];
    float* out = (float*)d_out;

    char* ws = (char*)d_ws;
    size_t off = 0;
    auto alloc = [&](size_t bytes) -> void* {
        void* p = (void*)(ws + off);
        off = (off + bytes + 255) & ~(size_t)255;
        return p;
    };
    float* dinv   = (float*)alloc((size_t)NN * 4);
    float* Binv   = (float*)alloc((size_t)NH * 4);
    float* Dinv   = (float*)alloc((size_t)NN * 4);
    int*   rpAll  = (int*)alloc((size_t)(NT + 1) * 4);
    int*   colAll = (int*)alloc((size_t)(NE + 2 * (size_t)NI) * 4);  // 14.4 MB
    int*   gcur   = (int*)alloc((size_t)NBUKT * 4);
    // union region: pairs slack (22.5 MB, build-time) / A16,X1,XH16 (38.4 MB)
    char*  U      = (char*)alloc((size_t)3 * NN * D * 2);
    u32*   pairs  = (u32*)U;
    u16*   A16    = (u16*)U;
    u16*   X1     = (u16*)(U + (size_t)NN * D * 2);
    u16*   XH16   = (u16*)(U + (size_t)2 * NN * D * 2);
    u16*   M16    = (u16*)alloc((size_t)NH * D * 2);
    u16*   X2b    = (u16*)alloc((size_t)NN * C * 2);   // 8 MB
    u16*   XH2b   = (u16*)alloc((size_t)NN * C * 2);

    const int B = 256;
    int gNN  = (NN + 255) / 256;
    int gN64 = NN * 64 / 256;          // 25000 blocks, 1 wave per node
    int gH64 = NH * 64 / 256;          // 2500

    // ---- build CSR + degrees (LDS multisplit, fine sort incl. base scan) ----
    hipMemsetAsync(gcur, 0, (size_t)NBUKT * 4, stream);
    k_build<<<3 * NBLK, B, 0, stream>>>(esrc, edst, hid, hnode, gcur, pairs);
    k_p3<<<NBUKT, B, 0, stream>>>(pairs, gcur, rpAll, colAll, dinv, Binv, Dinv);

    // ---- layer 1 GCN: x1 = relu(dinv*(self + gather) + b1g) ----
    k_gemm<64, true, false><<<gNN, B, 0, stream>>>(x, W1g, dinv, A16, NN);
    k_gcn_gather<64, true, true><<<gN64, B, 0, stream>>>(rpAll, colAll, A16, dinv, b1g, X1, NN);

    // ---- layer 1 hypergraph on x1 ----
    k_gemm<64, false, true><<<gNN, B, 0, stream>>>(X1, W1h, nullptr, A16, NN);
    k_hypA<64><<<gH64, B, 0, stream>>>(rpAll + OFF_H, colAll, A16, Binv, M16, NH);
    k_hypB<64, true, true><<<gN64, B, 0, stream>>>(rpAll + OFF_N, colAll, M16, Dinv, b1h, XH16, NN);

    // ---- attn1 fused into layer-2 GCN GEMM: G2 = (attn(x1,xh)@W2g)*dinv ----
    k_gemm_attn<<<gNN, B, 0, stream>>>(X1, XH16, aw1, W2g, dinv, A16, NN);
    k_gcn_gather<40, false, true><<<gN64, B, 0, stream>>>(rpAll, colAll, A16, dinv, b2g, X2b, NN);

    // ---- layer 2 hypergraph on x_hyper ----
    k_gemm<40, false, true><<<gNN, B, 0, stream>>>(XH16, W2h, nullptr, X1, NN);  // X1 = G4
    k_hypA<40><<<gH64, B, 0, stream>>>(rpAll + OFF_H, colAll, X1, Binv, M16, NH);
    k_hypB<40, false, true><<<gN64, B, 0, stream>>>(rpAll + OFF_N, colAll, M16, Dinv, b2h, XH2b, NN);

    // ---- attention 2 + log_softmax -> out ----
    k_attn_lsm<<<gN64, B, 0, stream>>>(X2b, XH2b, aw2, out, NN);
}